// Round 6
// baseline (4581.107 us; speedup 1.0000x reference)
//
#include <hip/hip_runtime.h>
#include <hip/hip_bf16.h>
#include <cstdint>
#include <cstddef>

#define BB 4
#define CC 192
#define NHEAD 6
#define WSZ 16
#define SSH 8
#define NTOK 256
#define HD 32
#define HWPIX 16384
#define TTOT 65536
#define WWID 128
#define SCALE_Q 0.17677669529663687f
#define CONV_SC 0.01f

typedef __hip_bfloat16 bf16;

__device__ __forceinline__ float b2f(bf16 v) { return __bfloat162float(v); }
__device__ __forceinline__ bf16 f2b(float v) { return __float2bfloat16(v); }
__device__ __forceinline__ float lo16(unsigned u) {
  union { unsigned i; float f; } c; c.i = u << 16; return c.f;
}
__device__ __forceinline__ float hi16(unsigned u) {
  union { unsigned i; float f; } c; c.i = u & 0xffff0000u; return c.f;
}
__device__ __forceinline__ unsigned short f2bu(float f) {
  bf16 h = __float2bfloat16(f);
  return *reinterpret_cast<unsigned short*>(&h);
}
__device__ __forceinline__ unsigned pack2(float a, float b) {
  return (unsigned)f2bu(a) | ((unsigned)f2bu(b) << 16);
}
__device__ __forceinline__ float gelu_exact(float x) {
  return 0.5f * x * (1.0f + erff(x * 0.7071067811865475f));
}

// ---------------- K1: LayerNorm1 (x fp32 -> xn bf16). 1 wave per token -----
__global__ __launch_bounds__(256) void k_ln1(const float* __restrict__ x,
                                             const float* __restrict__ g,
                                             const float* __restrict__ b,
                                             bf16* __restrict__ xn) {
  int wv = threadIdx.x >> 6, lane = threadIdx.x & 63;
  int tok = blockIdx.x * 4 + wv;
  size_t row = (size_t)tok * CC;
  float v0 = x[row + lane], v1 = x[row + lane + 64], v2 = x[row + lane + 128];
  float s = v0 + v1 + v2, ss = v0 * v0 + v1 * v1 + v2 * v2;
#pragma unroll
  for (int off = 1; off < 64; off <<= 1) {
    s += __shfl_xor(s, off, 64);
    ss += __shfl_xor(ss, off, 64);
  }
  float mean = s * (1.0f / CC);
  float rstd = rsqrtf(ss * (1.0f / CC) - mean * mean + 1e-5f);
  xn[row + lane]       = f2b((v0 - mean) * rstd * g[lane]       + b[lane]);
  xn[row + lane + 64]  = f2b((v1 - mean) * rstd * g[lane + 64]  + b[lane + 64]);
  xn[row + lane + 128] = f2b((v2 - mean) * rstd * g[lane + 128] + b[lane + 128]);
}

// ---------------- K2: bias transpose biasT[h][key][query] (fp32) ------------
__global__ __launch_bounds__(256) void k_bias(const int* __restrict__ rpi,
                                              const float* __restrict__ rpb,
                                              float* __restrict__ biasT) {
  int n = threadIdx.x;
  int h = blockIdx.x >> 8;
  int jk = blockIdx.x & 255;
  biasT[(size_t)blockIdx.x * 256 + n] = rpb[rpi[n * 256 + jk] * NHEAD + h];
}

#define DOT8(u, b) (q[b+0]*lo16(u.x) + q[b+1]*hi16(u.x) + q[b+2]*lo16(u.y) + q[b+3]*hi16(u.y) + \
                    q[b+4]*lo16(u.z) + q[b+5]*hi16(u.z) + q[b+6]*lo16(u.w) + q[b+7]*hi16(u.w))

#define VMAC(u, b, p)                                 \
  { o[b + 0] += p * lo16(u.x); o[b + 1] += p * hi16(u.x); \
    o[b + 2] += p * lo16(u.y); o[b + 3] += p * hi16(u.y); \
    o[b + 4] += p * lo16(u.z); o[b + 5] += p * hi16(u.z); \
    o[b + 6] += p * lo16(u.w); o[b + 7] += p * hi16(u.w); }

#define VCR(u, b, cr)                                           \
  { o[b + 0] = o[b + 0] * cr + lo16(u.x); o[b + 1] = o[b + 1] * cr + hi16(u.x); \
    o[b + 2] = o[b + 2] * cr + lo16(u.y); o[b + 3] = o[b + 3] * cr + hi16(u.y); \
    o[b + 4] = o[b + 4] * cr + lo16(u.z); o[b + 5] = o[b + 5] * cr + hi16(u.z); \
    o[b + 6] = o[b + 6] * cr + lo16(u.w); o[b + 7] = o[b + 7] * cr + hi16(u.w); }

// --- K3: fused window attention: per-window QKV + softmax + proj + residual -
// grid = 256 windows, block = 256 threads (1 token each). LDS = 159744 B.
__global__ __launch_bounds__(256, 1) void k_winattn(
    const bf16* __restrict__ xn, const float* __restrict__ wq,
    const float* __restrict__ qb, const float* __restrict__ biasT,
    const float* __restrict__ pw, const float* __restrict__ pb,
    const float* __restrict__ x, float* __restrict__ y) {
  __shared__ unsigned short aoT[256 * 200];   // 102400 B [token][6*32 pad 200]
  __shared__ unsigned short KT[256 * 32];     //  16384 B
  __shared__ unsigned short VT[256 * 32];     //  16384 B
  __shared__ float Wsf[192 * 32];             //  24576 B

  int n = threadIdx.x;
  int wdx = blockIdx.x;
  int wb = wdx >> 6, wl = wdx & 63;
  int wr = wl >> 3, wc = wl & 7;
  // token n -> shifted-image coords -> global pixel (inverse roll)
  int hs = (wr << 4) + (n >> 4), wsx = (wc << 4) + (n & 15);
  int gh = (hs + SSH) & 127, gw = (wsx + SSH) & 127;
  size_t pix = (size_t)wb * HWPIX + (size_t)gh * WWID + gw;
  // this token's xn row (192 bf16 = 24 uint4) held in registers all kernel
  uint4 rowv[24];
  {
    const uint4* rp = (const uint4*)(xn + pix * CC);
#pragma unroll
    for (int c = 0; c < 24; ++c) rowv[c] = rp[c];
  }
  int rid_n = ((hs >= 112) + (hs >= 120)) * 3 + ((wsx >= 112) + (wsx >= 120));

  float q[32], o[32];
  const int SOFF[3] = {192, 384, 0};  // K, V, Q column offsets in qkv_w

  for (int h = 0; h < NHEAD; ++h) {
    // ---- compute K tile, V tile (LDS bf16) and q (regs) for head h ----
    for (int sel = 0; sel < 3; ++sel) {
      __syncthreads();  // protect Wsf and prev head's KT/VT from overwrite
      if (n < 192) {
        const float4* s = (const float4*)(wq + (size_t)n * 576 + SOFF[sel] + h * 32);
        float4* dst = (float4*)&Wsf[n * 32];
#pragma unroll
        for (int i = 0; i < 8; ++i) dst[i] = s[i];
      }
      __syncthreads();
      float acc[32];
#pragma unroll
      for (int d = 0; d < 32; ++d) acc[d] = 0.f;
#pragma unroll
      for (int c = 0; c < 24; ++c) {
        uint4 u = rowv[c];
        float xv[8] = {lo16(u.x), hi16(u.x), lo16(u.y), hi16(u.y),
                       lo16(u.z), hi16(u.z), lo16(u.w), hi16(u.w)};
#pragma unroll
        for (int j = 0; j < 8; ++j) {
          const float4* w4 = (const float4*)&Wsf[(c * 8 + j) * 32];
          float f = xv[j];
#pragma unroll
          for (int i = 0; i < 8; ++i) {
            float4 w = w4[i];
            acc[i * 4 + 0] += f * w.x; acc[i * 4 + 1] += f * w.y;
            acc[i * 4 + 2] += f * w.z; acc[i * 4 + 3] += f * w.w;
          }
        }
      }
      int boff = SOFF[sel] + h * 32;
      if (sel == 2) {
#pragma unroll
        for (int d = 0; d < 32; ++d) q[d] = (acc[d] + qb[boff + d]) * SCALE_Q;
      } else {
#pragma unroll
        for (int d = 0; d < 32; ++d) acc[d] += qb[boff + d];
        uint4 pk[4];
#pragma unroll
        for (int i = 0; i < 4; ++i) {
          pk[i].x = pack2(acc[i * 8 + 0], acc[i * 8 + 1]);
          pk[i].y = pack2(acc[i * 8 + 2], acc[i * 8 + 3]);
          pk[i].z = pack2(acc[i * 8 + 4], acc[i * 8 + 5]);
          pk[i].w = pack2(acc[i * 8 + 6], acc[i * 8 + 7]);
        }
        uint4* kd = (uint4*)&((sel == 0 ? KT : VT)[n * 32]);
        kd[0] = pk[0]; kd[1] = pk[1]; kd[2] = pk[2]; kd[3] = pk[3];
      }
    }
    // KT/VT writes separated from reads by the sel-loop barriers above.
    // ---- online softmax over 256 keys ----
    const float* bbh = biasT + (size_t)h * (NTOK * NTOK) + n;
    float m = -1.0e30f, l = 0.f;
#pragma unroll
    for (int d = 0; d < 32; ++d) o[d] = 0.f;
    for (int jk = 0; jk < NTOK; ++jk) {
      const uint4* kr = (const uint4*)&KT[jk * 32];
      uint4 k0 = kr[0], k1 = kr[1], k2 = kr[2], k3 = kr[3];
      float s = DOT8(k0, 0) + DOT8(k1, 8) + DOT8(k2, 16) + DOT8(k3, 24);
      s += bbh[jk * 256];
      int hj = (wr << 4) + (jk >> 4), wj = (wc << 4) + (jk & 15);
      int rid_j = ((hj >= 112) + (hj >= 120)) * 3 + ((wj >= 112) + (wj >= 120));
      s += (rid_j != rid_n) ? -100.f : 0.f;
      const uint4* vr = (const uint4*)&VT[jk * 32];
      uint4 v0 = vr[0], v1 = vr[1], v2 = vr[2], v3 = vr[3];
      if (s <= m) {
        float p = __expf(s - m);
        l += p;
        VMAC(v0, 0, p) VMAC(v1, 8, p) VMAC(v2, 16, p) VMAC(v3, 24, p)
      } else {
        float corr = __expf(m - s);
        l = l * corr + 1.f;
        VCR(v0, 0, corr) VCR(v1, 8, corr) VCR(v2, 16, corr) VCR(v3, 24, corr)
        m = s;
      }
    }
    float inv = 1.f / l;
    uint4 pk[4];
#pragma unroll
    for (int i = 0; i < 4; ++i) {
      pk[i].x = pack2(o[i * 8 + 0] * inv, o[i * 8 + 1] * inv);
      pk[i].y = pack2(o[i * 8 + 2] * inv, o[i * 8 + 3] * inv);
      pk[i].z = pack2(o[i * 8 + 4] * inv, o[i * 8 + 5] * inv);
      pk[i].w = pack2(o[i * 8 + 6] * inv, o[i * 8 + 7] * inv);
    }
    uint4* ad = (uint4*)&aoT[n * 200 + h * 32];  // byte 400n+64h: 16B aligned
    ad[0] = pk[0]; ad[1] = pk[1]; ad[2] = pk[2]; ad[3] = pk[3];
  }
  __syncthreads();
  // ---- proj GEMM + window-reverse + roll-back + x residual -> y (fp32) ----
  int wv = n >> 6, lane = n & 63;
  for (int tt = 0; tt < 4; ++tt) {
    int r0 = (wv << 6) + (tt << 4);
    float a0[16], a1[16], a2[16];
    float p0 = pb[lane], p1 = pb[lane + 64], p2 = pb[lane + 128];
#pragma unroll
    for (int j = 0; j < 16; ++j) { a0[j] = p0; a1[j] = p1; a2[j] = p2; }
    for (int kk = 0; kk < CC; ++kk) {
      float w0 = pw[kk * CC + lane];
      float w1 = pw[kk * CC + lane + 64];
      float w2 = pw[kk * CC + lane + 128];
#pragma unroll
      for (int j = 0; j < 16; ++j) {
        float v = lo16((unsigned)aoT[(r0 + j) * 200 + kk]);
        a0[j] += v * w0; a1[j] += v * w1; a2[j] += v * w2;
      }
    }
#pragma unroll
    for (int j = 0; j < 16; ++j) {
      int r = r0 + j;
      int hs2 = (wr << 4) + (r >> 4), ws2 = (wc << 4) + (r & 15);
      int gh2 = (hs2 + SSH) & 127, gw2 = (ws2 + SSH) & 127;
      size_t drow = ((size_t)wb * HWPIX + (size_t)gh2 * WWID + gw2) * CC;
      y[drow + lane]       = x[drow + lane]       + a0[j];
      y[drow + lane + 64]  = x[drow + lane + 64]  + a1[j];
      y[drow + lane + 128] = x[drow + lane + 128] + a2[j];
    }
  }
}

// ------ K4: conv3x3 192->64 + GELU, ONE batch. block=64 (co), 4 px/thread ---
__global__ __launch_bounds__(64) void k_conv1(const bf16* __restrict__ xn,
                                              const float* __restrict__ w,
                                              const float* __restrict__ bias,
                                              bf16* __restrict__ cv1, int b) {
  int co = threadIdx.x;
  int bi = blockIdx.x;
  int wseg = bi & 31;
  int hh = bi >> 5;          // 0..127
  int w0 = wseg * 4;
  float a0 = bias[co], a1 = a0, a2 = a0, a3 = a0;
  for (int kh = 0; kh < 3; ++kh) {
    int gh = hh + kh - 1;
    if ((unsigned)gh >= 128u) continue;
    const bf16* xrow = xn + ((size_t)b * HWPIX + (size_t)gh * WWID) * CC;
    const float* wrow = w + (size_t)(kh * 3) * CC * 64 + co;
    for (int ci = 0; ci < CC; ++ci) {
      float x0 = (w0 >= 1)      ? b2f(xrow[(w0 - 1) * CC + ci]) : 0.f;
      float x1 = b2f(xrow[(w0 + 0) * CC + ci]);
      float x2 = b2f(xrow[(w0 + 1) * CC + ci]);
      float x3 = b2f(xrow[(w0 + 2) * CC + ci]);
      float x4 = b2f(xrow[(w0 + 3) * CC + ci]);
      float x5 = (w0 + 4 < 128) ? b2f(xrow[(w0 + 4) * CC + ci]) : 0.f;
      float wv0 = wrow[(0 * CC + ci) * 64];
      float wv1 = wrow[(1 * CC + ci) * 64];
      float wv2 = wrow[(2 * CC + ci) * 64];
      a0 += x0 * wv0 + x1 * wv1 + x2 * wv2;
      a1 += x1 * wv0 + x2 * wv1 + x3 * wv2;
      a2 += x2 * wv0 + x3 * wv1 + x4 * wv2;
      a3 += x3 * wv0 + x4 * wv1 + x5 * wv2;
    }
  }
  size_t orow = ((size_t)hh * WWID + w0) * 64 + co;   // batch-local
  cv1[orow]       = f2b(gelu_exact(a0));
  cv1[orow + 64]  = f2b(gelu_exact(a1));
  cv1[orow + 128] = f2b(gelu_exact(a2));
  cv1[orow + 192] = f2b(gelu_exact(a3));
}

// ------ K5: conv3x3 64->192 + bias, ONE batch. block=192 (co), 4 px/thread --
// cv2 overlays xn's batch-b slice (xn dead after winattn+conv1 of batch b).
__global__ __launch_bounds__(192) void k_conv2(const bf16* __restrict__ cv1,
                                               const float* __restrict__ w,
                                               const float* __restrict__ bias,
                                               bf16* cv2, int b) {
  int co = threadIdx.x;
  int bi = blockIdx.x;
  int wseg = bi & 31;
  int hh = bi >> 5;          // 0..127
  int w0 = wseg * 4;
  float a0 = bias[co], a1 = a0, a2 = a0, a3 = a0;
  for (int kh = 0; kh < 3; ++kh) {
    int gh = hh + kh - 1;
    if ((unsigned)gh >= 128u) continue;
    const bf16* xrow = cv1 + (size_t)gh * WWID * 64;   // batch-local
    const float* wrow = w + (size_t)(kh * 3) * 64 * CC + co;
    for (int ci = 0; ci < 64; ++ci) {
      float x0 = (w0 >= 1)      ? b2f(xrow[(w0 - 1) * 64 + ci]) : 0.f;
      float x1 = b2f(xrow[(w0 + 0) * 64 + ci]);
      float x2 = b2f(xrow[(w0 + 1) * 64 + ci]);
      float x3 = b2f(xrow[(w0 + 2) * 64 + ci]);
      float x4 = b2f(xrow[(w0 + 3) * 64 + ci]);
      float x5 = (w0 + 4 < 128) ? b2f(xrow[(w0 + 4) * 64 + ci]) : 0.f;
      float wv0 = wrow[(0 * 64 + ci) * CC];
      float wv1 = wrow[(1 * 64 + ci) * CC];
      float wv2 = wrow[(2 * 64 + ci) * CC];
      a0 += x0 * wv0 + x1 * wv1 + x2 * wv2;
      a1 += x1 * wv0 + x2 * wv1 + x3 * wv2;
      a2 += x2 * wv0 + x3 * wv1 + x4 * wv2;
      a3 += x3 * wv0 + x4 * wv1 + x5 * wv2;
    }
  }
  size_t orow = ((size_t)b * HWPIX + (size_t)hh * WWID + w0) * CC + co;
  cv2[orow]          = f2b(a0);
  cv2[orow + CC]     = f2b(a1);
  cv2[orow + 2 * CC] = f2b(a2);
  cv2[orow + 3 * CC] = f2b(a3);
}

// ---------------- K6: global average pool (sum into pooled, pre-zeroed) ----
__global__ __launch_bounds__(256) void k_pool(const bf16* __restrict__ cv2,
                                              float* __restrict__ pooled) {
  __shared__ float sacc[CC];
  int t = threadIdx.x;
  if (t < CC) sacc[t] = 0.f;
  __syncthreads();
  int b = blockIdx.x >> 7;
  int pc = blockIdx.x & 127;
  const bf16* base = cv2 + (size_t)b * HWPIX * CC + (size_t)pc * 128 * CC;
  for (int it = 0; it < 96; ++it) {
    int e = it * 256 + t;
    atomicAdd(&sacc[e % CC], b2f(base[e]));
  }
  __syncthreads();
  if (t < CC) atomicAdd(&pooled[b * CC + t], sacc[t]);
}

// ---------------- K7: channel attention weights ----------------
__global__ __launch_bounds__(192) void k_ca(const float* __restrict__ pooled,
                                            const float* __restrict__ w1,
                                            const float* __restrict__ b1,
                                            const float* __restrict__ w2,
                                            const float* __restrict__ b2,
                                            float* __restrict__ ca) {
  __shared__ float pld[CC];
  __shared__ float t1[6];
  int t = threadIdx.x, b = blockIdx.x;
  pld[t] = pooled[b * CC + t] * (1.0f / HWPIX);
  __syncthreads();
  if (t < 6) {
    float s = b1[t];
    for (int c = 0; c < CC; ++c) s += pld[c] * w1[c * 6 + t];
    t1[t] = fmaxf(s, 0.f);
  }
  __syncthreads();
  float s = b2[t];
#pragma unroll
  for (int k = 0; k < 6; ++k) s += t1[k] * w2[k * CC + t];
  ca[b * CC + t] = 1.f / (1.f + __expf(-s));
}

// --- K8: LN2 + MLP + residual; folds yf = y + cv2*ca*CONV_SC on the fly ---
// NOTE: y and out alias (both d_out, fp32) -> no __restrict__ on them. Safe:
// per-thread same-address read-then-write; blocks touch disjoint rows; all
// phase-1 y reads precede the barriers before the epilogue writes.
__global__ __launch_bounds__(256) void k_mlp(const float* y,
                                             const bf16* __restrict__ cv2,
                                             const float* __restrict__ ca,
                                             const float* __restrict__ g2,
                                             const float* __restrict__ b2,
                                             const float* __restrict__ fw1,
                                             const float* __restrict__ fb1,
                                             const float* __restrict__ fw2,
                                             const float* __restrict__ fb2,
                                             float* out) {
  __shared__ float ynsT[CC * 20];
  __shared__ float hsT[768 * 20];
  int t = threadIdx.x;
  int tok0 = blockIdx.x * 16;
  const float* cab = ca + (tok0 >> 14) * CC;  // all 16 toks in same batch
  int wv = t >> 6, lane = t & 63;
  for (int q = 0; q < 4; ++q) {
    int tk = wv * 4 + q;
    size_t row = (size_t)(tok0 + tk) * CC;
    float v0 = y[row + lane]       + b2f(cv2[row + lane])       * cab[lane]       * CONV_SC;
    float v1 = y[row + lane + 64]  + b2f(cv2[row + lane + 64])  * cab[lane + 64]  * CONV_SC;
    float v2 = y[row + lane + 128] + b2f(cv2[row + lane + 128]) * cab[lane + 128] * CONV_SC;
    float s = v0 + v1 + v2, ss = v0 * v0 + v1 * v1 + v2 * v2;
#pragma unroll
    for (int off = 1; off < 64; off <<= 1) {
      s += __shfl_xor(s, off, 64);
      ss += __shfl_xor(ss, off, 64);
    }
    float mean = s * (1.0f / CC);
    float rstd = rsqrtf(ss * (1.0f / CC) - mean * mean + 1e-5f);
    ynsT[lane * 20 + tk]         = (v0 - mean) * rstd * g2[lane]       + b2[lane];
    ynsT[(lane + 64) * 20 + tk]  = (v1 - mean) * rstd * g2[lane + 64]  + b2[lane + 64];
    ynsT[(lane + 128) * 20 + tk] = (v2 - mean) * rstd * g2[lane + 128] + b2[lane + 128];
  }
  __syncthreads();
  float acc[3][16];
#pragma unroll
  for (int j = 0; j < 3; ++j) {
    float bv = fb1[t + j * 256];
#pragma unroll
    for (int k = 0; k < 16; ++k) acc[j][k] = bv;
  }
  for (int kk = 0; kk < CC; ++kk) {
    float xs16[16];
    const float4* xr = (const float4*)&ynsT[kk * 20];
    *(float4*)&xs16[0] = xr[0]; *(float4*)&xs16[4] = xr[1];
    *(float4*)&xs16[8] = xr[2]; *(float4*)&xs16[12] = xr[3];
    float w0 = fw1[kk * 768 + t];
    float w1 = fw1[kk * 768 + t + 256];
    float w2 = fw1[kk * 768 + t + 512];
#pragma unroll
    for (int k = 0; k < 16; ++k) {
      float xv = xs16[k];
      acc[0][k] += xv * w0; acc[1][k] += xv * w1; acc[2][k] += xv * w2;
    }
  }
#pragma unroll
  for (int j = 0; j < 3; ++j)
    for (int k = 0; k < 16; ++k)
      hsT[(t + j * 256) * 20 + k] = gelu_exact(acc[j][k]);
  __syncthreads();
  if (t < CC) {
    float acc2[16];
    float bv = fb2[t];
#pragma unroll
    for (int k = 0; k < 16; ++k) acc2[k] = bv;
    for (int kk = 0; kk < 768; ++kk) {
      float hs16[16];
      const float4* hr = (const float4*)&hsT[kk * 20];
      *(float4*)&hs16[0] = hr[0]; *(float4*)&hs16[4] = hr[1];
      *(float4*)&hs16[8] = hr[2]; *(float4*)&hs16[12] = hr[3];
      float w = fw2[kk * CC + t];
#pragma unroll
      for (int k = 0; k < 16; ++k) acc2[k] += hs16[k] * w;
    }
#pragma unroll
    for (int k = 0; k < 16; ++k) {
      size_t row = (size_t)(tok0 + k) * CC;
      float yf = y[row + t] + b2f(cv2[row + t]) * cab[t] * CONV_SC;
      out[row + t] = yf + acc2[k];
    }
  }
}

extern "C" void kernel_launch(void* const* d_in, const int* in_sizes, int n_in,
                              void* d_out, int out_size, void* d_ws, size_t ws_size,
                              hipStream_t stream) {
  const float* x      = (const float*)d_in[0];
  const float* qkv_w  = (const float*)d_in[1];
  const float* qkv_b  = (const float*)d_in[2];
  const float* proj_w = (const float*)d_in[3];
  const float* proj_b = (const float*)d_in[4];
  const float* rpb    = (const float*)d_in[5];
  const float* n1w    = (const float*)d_in[6];
  const float* n1b    = (const float*)d_in[7];
  const float* n2w    = (const float*)d_in[8];
  const float* n2b    = (const float*)d_in[9];
  const float* c1w    = (const float*)d_in[10];
  const float* c1b    = (const float*)d_in[11];
  const float* c2w    = (const float*)d_in[12];
  const float* c2b    = (const float*)d_in[13];
  const float* ca1w   = (const float*)d_in[14];
  const float* ca1b   = (const float*)d_in[15];
  const float* ca2w   = (const float*)d_in[16];
  const float* ca2b   = (const float*)d_in[17];
  const float* fc1w   = (const float*)d_in[18];
  const float* fc1b   = (const float*)d_in[19];
  const float* fc2w   = (const float*)d_in[20];
  const float* fc2b   = (const float*)d_in[21];
  const int*   rpi    = (const int*)d_in[22];
  (void)in_sizes; (void)n_in; (void)out_size; (void)ws_size;

  // ---- workspace layout: peak 28,841,984 B (~27.5 MiB) ----
  char* wsb = (char*)d_ws;
  bf16*  xn    = (bf16*)(wsb + 0);            // 25,165,824 B (ln1 -> winattn, conv1)
  bf16*  cv2   = (bf16*)(wsb + 0);            // alias xn (per-batch overwrite after use)
  float* biasT = (float*)(wsb + 25165824);    //  1,572,864 B
  bf16*  cv1s  = (bf16*)(wsb + 26738688);     //  2,097,152 B (one batch, reused 4x)
  float* pool  = (float*)(wsb + 28835840);    //      3,072 B
  float* cavec = (float*)(wsb + 28838912);    //      3,072 B
  float* y     = (float*)d_out;               // winattn -> mlp (aliases out, fp32)
  float* out   = (float*)d_out;

  k_ln1<<<TTOT / 4, 256, 0, stream>>>(x, n1w, n1b, xn);
  k_bias<<<NHEAD * NTOK, 256, 0, stream>>>(rpi, rpb, biasT);
  k_winattn<<<BB * 64, 256, 0, stream>>>(xn, qkv_w, qkv_b, biasT, proj_w, proj_b, x, y);
  // conv branch per batch: conv1(b) reads xn[b]; conv2(b) overwrites xn[b] with cv2[b]
  for (int b = 0; b < BB; ++b) {
    k_conv1<<<4096, 64, 0, stream>>>(xn, c1w, c1b, cv1s, b);
    k_conv2<<<4096, 192, 0, stream>>>(cv1s, c2w, c2b, cv2, b);
  }
  hipMemsetAsync(pool, 0, BB * CC * sizeof(float), stream);
  k_pool<<<512, 256, 0, stream>>>(cv2, pool);
  k_ca<<<BB, 192, 0, stream>>>(pool, ca1w, ca1b, ca2w, ca2b, cavec);
  k_mlp<<<TTOT / 16, 256, 0, stream>>>(y, cv2, cavec, n2w, n2b, fc1w, fc1b, fc2w, fc2b, out);
}

// Round 7
// 3026.726 us; speedup vs baseline: 1.5136x; 1.5136x over previous
//
#include <hip/hip_runtime.h>
#include <hip/hip_bf16.h>
#include <cstdint>
#include <cstddef>

#define BB 4
#define CC 192
#define NHEAD 6
#define WSZ 16
#define SSH 8
#define NTOK 256
#define HD 32
#define HWPIX 16384
#define TTOT 65536
#define WWID 128
#define SCALE_Q 0.17677669529663687f
#define CONV_SC 0.01f

typedef __hip_bfloat16 bf16;

__device__ __forceinline__ float b2f(bf16 v) { return __bfloat162float(v); }
__device__ __forceinline__ bf16 f2b(float v) { return __float2bfloat16(v); }
__device__ __forceinline__ float lo16(unsigned u) {
  union { unsigned i; float f; } c; c.i = u << 16; return c.f;
}
__device__ __forceinline__ float hi16(unsigned u) {
  union { unsigned i; float f; } c; c.i = u & 0xffff0000u; return c.f;
}
__device__ __forceinline__ unsigned short f2bu(float f) {
  bf16 h = __float2bfloat16(f);
  return *reinterpret_cast<unsigned short*>(&h);
}
__device__ __forceinline__ unsigned pack2(float a, float b) {
  return (unsigned)f2bu(a) | ((unsigned)f2bu(b) << 16);
}
__device__ __forceinline__ float gelu_exact(float x) {
  return 0.5f * x * (1.0f + erff(x * 0.7071067811865475f));
}

// ---------------- K1: LayerNorm1 (x fp32 -> xn bf16). 1 wave per token -----
__global__ __launch_bounds__(256) void k_ln1(const float* __restrict__ x,
                                             const float* __restrict__ g,
                                             const float* __restrict__ b,
                                             bf16* __restrict__ xn) {
  int wv = threadIdx.x >> 6, lane = threadIdx.x & 63;
  int tok = blockIdx.x * 4 + wv;
  size_t row = (size_t)tok * CC;
  float v0 = x[row + lane], v1 = x[row + lane + 64], v2 = x[row + lane + 128];
  float s = v0 + v1 + v2, ss = v0 * v0 + v1 * v1 + v2 * v2;
#pragma unroll
  for (int off = 1; off < 64; off <<= 1) {
    s += __shfl_xor(s, off, 64);
    ss += __shfl_xor(ss, off, 64);
  }
  float mean = s * (1.0f / CC);
  float rstd = rsqrtf(ss * (1.0f / CC) - mean * mean + 1e-5f);
  xn[row + lane]       = f2b((v0 - mean) * rstd * g[lane]       + b[lane]);
  xn[row + lane + 64]  = f2b((v1 - mean) * rstd * g[lane + 64]  + b[lane + 64]);
  xn[row + lane + 128] = f2b((v2 - mean) * rstd * g[lane + 128] + b[lane + 128]);
}

// ---------------- K2: bias transpose biasT[h][key][query] (fp32) ------------
__global__ __launch_bounds__(256) void k_bias(const int* __restrict__ rpi,
                                              const float* __restrict__ rpb,
                                              float* __restrict__ biasT) {
  int n = threadIdx.x;
  int h = blockIdx.x >> 8;
  int jk = blockIdx.x & 255;
  biasT[(size_t)blockIdx.x * 256 + n] = rpb[rpi[n * 256 + jk] * NHEAD + h];
}

// --------- K3: QKV GEMM, writing gathered [win][head][tok][32] layout -------
// grid 4096 (16 tok/block), block 192. Shift+partition folded into the store.
__global__ __launch_bounds__(192) void k_qkvg(const bf16* __restrict__ xn,
                                              const float* __restrict__ wq,
                                              const float* __restrict__ qb,
                                              bf16* __restrict__ Qg,
                                              bf16* __restrict__ Kg,
                                              bf16* __restrict__ Vg) {
  __shared__ float xsT[CC * 20];
  int t = threadIdx.x;
  int tok0 = blockIdx.x * 16;
  for (int i = 0; i < 16; ++i)
    xsT[t * 20 + i] = b2f(xn[(size_t)(tok0 + i) * CC + t]);
  __syncthreads();
  float acc0[16], acc1[16], acc2[16];
  float b0 = qb[t], b1v = qb[t + 192], b2v = qb[t + 384];
#pragma unroll
  for (int k = 0; k < 16; ++k) { acc0[k] = b0; acc1[k] = b1v; acc2[k] = b2v; }
  for (int kk = 0; kk < CC; ++kk) {
    float xs16[16];
    const float4* xr = (const float4*)&xsT[kk * 20];
    *(float4*)&xs16[0] = xr[0]; *(float4*)&xs16[4] = xr[1];
    *(float4*)&xs16[8] = xr[2]; *(float4*)&xs16[12] = xr[3];
    float w0 = wq[kk * 576 + t];
    float w1 = wq[kk * 576 + t + 192];
    float w2 = wq[kk * 576 + t + 384];
#pragma unroll
    for (int k = 0; k < 16; ++k) {
      float xv = xs16[k];
      acc0[k] += xv * w0; acc1[k] += xv * w1; acc2[k] += xv * w2;
    }
  }
  int hq = t >> 5, dq = t & 31;
  for (int k = 0; k < 16; ++k) {
    int tg = tok0 + k;
    int b = tg >> 14;
    int pix = tg & 16383;
    int gh = pix >> 7, gw = pix & 127;
    int hs = (gh + 120) & 127, wsx = (gw + 120) & 127;  // shifted coords
    int wdx = (b << 6) + ((hs >> 4) << 3) + (wsx >> 4);
    int ndx = ((hs & 15) << 4) + (wsx & 15);
    size_t off = (((size_t)wdx * NHEAD + hq) * NTOK + ndx) * HD + dq;
    Qg[off] = f2b(acc0[k] * SCALE_Q);
    Kg[off] = f2b(acc1[k]);
    Vg[off] = f2b(acc2[k]);
  }
}

#define DOT8(u, b) (q[b+0]*lo16(u.x) + q[b+1]*hi16(u.x) + q[b+2]*lo16(u.y) + q[b+3]*hi16(u.y) + \
                    q[b+4]*lo16(u.z) + q[b+5]*hi16(u.z) + q[b+6]*lo16(u.w) + q[b+7]*hi16(u.w))

#define VMAC(u, b, p)                                 \
  { o[b + 0] += p * lo16(u.x); o[b + 1] += p * hi16(u.x); \
    o[b + 2] += p * lo16(u.y); o[b + 3] += p * hi16(u.y); \
    o[b + 4] += p * lo16(u.z); o[b + 5] += p * hi16(u.z); \
    o[b + 6] += p * lo16(u.w); o[b + 7] += p * hi16(u.w); }

#define VCR(u, b, cr)                                           \
  { o[b + 0] = o[b + 0] * cr + lo16(u.x); o[b + 1] = o[b + 1] * cr + hi16(u.x); \
    o[b + 2] = o[b + 2] * cr + lo16(u.y); o[b + 3] = o[b + 3] * cr + hi16(u.y); \
    o[b + 4] = o[b + 4] * cr + lo16(u.z); o[b + 5] = o[b + 5] * cr + hi16(u.z); \
    o[b + 6] = o[b + 6] * cr + lo16(u.w); o[b + 7] = o[b + 7] * cr + hi16(u.w); }

// --------------- K4: windowed attention, 1 block per (window, head) ---------
// grid 1536, block 256. LDS 32 KB -> 4+ blocks/CU.
__global__ __launch_bounds__(256) void k_attn(const bf16* __restrict__ Qg,
                                              const bf16* __restrict__ Kg,
                                              const bf16* __restrict__ Vg,
                                              const float* __restrict__ biasT,
                                              bf16* __restrict__ AO) {
  __shared__ unsigned short KT[256 * 32];   // 16384 B
  __shared__ unsigned short VT[256 * 32];   // 16384 B
  int n = threadIdx.x;
  int wh = blockIdx.x;
  int wdx = wh / NHEAD;
  int h = wh - wdx * NHEAD;
  int wl = wdx & 63;
  int wr = wl >> 3, wc = wl & 7;
  // stage K/V rows (coalesced 64B per thread)
  {
    const uint4* kp = (const uint4*)(Kg + ((size_t)wh * NTOK + n) * HD);
    const uint4* vp = (const uint4*)(Vg + ((size_t)wh * NTOK + n) * HD);
    uint4* kd = (uint4*)&KT[n * 32];
    uint4* vd = (uint4*)&VT[n * 32];
    kd[0] = kp[0]; kd[1] = kp[1]; kd[2] = kp[2]; kd[3] = kp[3];
    vd[0] = vp[0]; vd[1] = vp[1]; vd[2] = vp[2]; vd[3] = vp[3];
  }
  // q row into registers
  float q[32];
  {
    const uint4* qp = (const uint4*)(Qg + ((size_t)wh * NTOK + n) * HD);
#pragma unroll
    for (int d = 0; d < 4; ++d) {
      uint4 u = qp[d];
      q[d * 8 + 0] = lo16(u.x); q[d * 8 + 1] = hi16(u.x);
      q[d * 8 + 2] = lo16(u.y); q[d * 8 + 3] = hi16(u.y);
      q[d * 8 + 4] = lo16(u.z); q[d * 8 + 5] = hi16(u.z);
      q[d * 8 + 6] = lo16(u.w); q[d * 8 + 7] = hi16(u.w);
    }
  }
  int hs = (wr << 4) + (n >> 4), wsx = (wc << 4) + (n & 15);
  int rid_n = ((hs >= 112) + (hs >= 120)) * 3 + ((wsx >= 112) + (wsx >= 120));
  const float* bbh = biasT + (size_t)h * (NTOK * NTOK) + n;
  __syncthreads();
  float m = -1.0e30f, l = 0.f;
  float o[32];
#pragma unroll
  for (int d = 0; d < 32; ++d) o[d] = 0.f;
  for (int jk = 0; jk < NTOK; ++jk) {
    const uint4* kr = (const uint4*)&KT[jk * 32];
    uint4 k0 = kr[0], k1 = kr[1], k2 = kr[2], k3 = kr[3];
    float s = DOT8(k0, 0) + DOT8(k1, 8) + DOT8(k2, 16) + DOT8(k3, 24);
    s += bbh[jk * 256];
    int hj = (wr << 4) + (jk >> 4), wj = (wc << 4) + (jk & 15);
    int rid_j = ((hj >= 112) + (hj >= 120)) * 3 + ((wj >= 112) + (wj >= 120));
    s += (rid_j != rid_n) ? -100.f : 0.f;
    const uint4* vr = (const uint4*)&VT[jk * 32];
    uint4 v0 = vr[0], v1 = vr[1], v2 = vr[2], v3 = vr[3];
    if (s <= m) {
      float p = __expf(s - m);
      l += p;
      VMAC(v0, 0, p) VMAC(v1, 8, p) VMAC(v2, 16, p) VMAC(v3, 24, p)
    } else {
      float corr = __expf(m - s);
      l = l * corr + 1.f;
      VCR(v0, 0, corr) VCR(v1, 8, corr) VCR(v2, 16, corr) VCR(v3, 24, corr)
      m = s;
    }
  }
  float inv = 1.f / l;
  uint4 pk[4];
#pragma unroll
  for (int i = 0; i < 4; ++i) {
    pk[i].x = pack2(o[i * 8 + 0] * inv, o[i * 8 + 1] * inv);
    pk[i].y = pack2(o[i * 8 + 2] * inv, o[i * 8 + 3] * inv);
    pk[i].z = pack2(o[i * 8 + 4] * inv, o[i * 8 + 5] * inv);
    pk[i].w = pack2(o[i * 8 + 6] * inv, o[i * 8 + 7] * inv);
  }
  uint4* ad = (uint4*)(AO + ((size_t)wdx * NTOK + n) * CC + h * HD);
  ad[0] = pk[0]; ad[1] = pk[1]; ad[2] = pk[2]; ad[3] = pk[3];
}

// ------- K5: proj GEMM + window-reverse + roll-back + x residual (fp32 y) ---
__global__ __launch_bounds__(256) void k_proj(const bf16* __restrict__ AO,
                                              const float* __restrict__ pw,
                                              const float* __restrict__ pb,
                                              const float* __restrict__ x,
                                              float* __restrict__ y) {
  __shared__ float as[4][CC];
  int wv = threadIdx.x >> 6, lane = threadIdx.x & 63;
  int r = blockIdx.x * 4 + wv;
  size_t arow = (size_t)r * CC;
  as[wv][lane]       = b2f(AO[arow + lane]);
  as[wv][lane + 64]  = b2f(AO[arow + lane + 64]);
  as[wv][lane + 128] = b2f(AO[arow + lane + 128]);
  __syncthreads();
  float a0 = pb[lane], a1 = pb[lane + 64], a2 = pb[lane + 128];
  for (int kk = 0; kk < CC; ++kk) {
    float v = as[wv][kk];
    a0 += v * pw[kk * CC + lane];
    a1 += v * pw[kk * CC + lane + 64];
    a2 += v * pw[kk * CC + lane + 128];
  }
  int wdx = r >> 8, n = r & 255;
  int wb = wdx >> 6, wl = wdx & 63;
  int hs = ((wl >> 3) << 4) + (n >> 4);
  int wsx = ((wl & 7) << 4) + (n & 15);
  int gh = (hs + SSH) & 127, gw = (wsx + SSH) & 127;
  size_t drow = ((size_t)wb * HWPIX + (size_t)gh * WWID + gw) * CC;
  y[drow + lane]       = x[drow + lane]       + a0;
  y[drow + lane + 64]  = x[drow + lane + 64]  + a1;
  y[drow + lane + 128] = x[drow + lane + 128] + a2;
}

// ---------------- K6: conv3x3 192->64 + GELU. block=64 (co), 4 px/thread ----
__global__ __launch_bounds__(64) void k_conv1(const bf16* __restrict__ xn,
                                              const float* __restrict__ w,
                                              const float* __restrict__ bias,
                                              bf16* __restrict__ cv1) {
  int co = threadIdx.x;
  int bi = blockIdx.x;
  int wseg = bi & 31;
  int hh = (bi >> 5) & 127;
  int b = bi >> 12;
  int w0 = wseg * 4;
  float a0 = bias[co], a1 = a0, a2 = a0, a3 = a0;
  for (int kh = 0; kh < 3; ++kh) {
    int gh = hh + kh - 1;
    if ((unsigned)gh >= 128u) continue;
    const bf16* xrow = xn + ((size_t)b * HWPIX + (size_t)gh * WWID) * CC;
    const float* wrow = w + (size_t)(kh * 3) * CC * 64 + co;
    for (int ci = 0; ci < CC; ++ci) {
      float x0 = (w0 >= 1)      ? b2f(xrow[(w0 - 1) * CC + ci]) : 0.f;
      float x1 = b2f(xrow[(w0 + 0) * CC + ci]);
      float x2 = b2f(xrow[(w0 + 1) * CC + ci]);
      float x3 = b2f(xrow[(w0 + 2) * CC + ci]);
      float x4 = b2f(xrow[(w0 + 3) * CC + ci]);
      float x5 = (w0 + 4 < 128) ? b2f(xrow[(w0 + 4) * CC + ci]) : 0.f;
      float wv0 = wrow[(0 * CC + ci) * 64];
      float wv1 = wrow[(1 * CC + ci) * 64];
      float wv2 = wrow[(2 * CC + ci) * 64];
      a0 += x0 * wv0 + x1 * wv1 + x2 * wv2;
      a1 += x1 * wv0 + x2 * wv1 + x3 * wv2;
      a2 += x2 * wv0 + x3 * wv1 + x4 * wv2;
      a3 += x3 * wv0 + x4 * wv1 + x5 * wv2;
    }
  }
  size_t orow = ((size_t)b * HWPIX + (size_t)hh * WWID + w0) * 64 + co;
  cv1[orow]       = f2b(gelu_exact(a0));
  cv1[orow + 64]  = f2b(gelu_exact(a1));
  cv1[orow + 128] = f2b(gelu_exact(a2));
  cv1[orow + 192] = f2b(gelu_exact(a3));
}

// ---------------- K7: conv3x3 64->192 + bias. block=192 (co), 4 px/thread ---
__global__ __launch_bounds__(192) void k_conv2(const bf16* __restrict__ cv1,
                                               const float* __restrict__ w,
                                               const float* __restrict__ bias,
                                               bf16* __restrict__ cv2) {
  int co = threadIdx.x;
  int bi = blockIdx.x;
  int wseg = bi & 31;
  int hh = (bi >> 5) & 127;
  int b = bi >> 12;
  int w0 = wseg * 4;
  float a0 = bias[co], a1 = a0, a2 = a0, a3 = a0;
  for (int kh = 0; kh < 3; ++kh) {
    int gh = hh + kh - 1;
    if ((unsigned)gh >= 128u) continue;
    const bf16* xrow = cv1 + ((size_t)b * HWPIX + (size_t)gh * WWID) * 64;
    const float* wrow = w + (size_t)(kh * 3) * 64 * CC + co;
    for (int ci = 0; ci < 64; ++ci) {
      float x0 = (w0 >= 1)      ? b2f(xrow[(w0 - 1) * 64 + ci]) : 0.f;
      float x1 = b2f(xrow[(w0 + 0) * 64 + ci]);
      float x2 = b2f(xrow[(w0 + 1) * 64 + ci]);
      float x3 = b2f(xrow[(w0 + 2) * 64 + ci]);
      float x4 = b2f(xrow[(w0 + 3) * 64 + ci]);
      float x5 = (w0 + 4 < 128) ? b2f(xrow[(w0 + 4) * 64 + ci]) : 0.f;
      float wv0 = wrow[(0 * 64 + ci) * CC];
      float wv1 = wrow[(1 * 64 + ci) * CC];
      float wv2 = wrow[(2 * 64 + ci) * CC];
      a0 += x0 * wv0 + x1 * wv1 + x2 * wv2;
      a1 += x1 * wv0 + x2 * wv1 + x3 * wv2;
      a2 += x2 * wv0 + x3 * wv1 + x4 * wv2;
      a3 += x3 * wv0 + x4 * wv1 + x5 * wv2;
    }
  }
  size_t orow = ((size_t)b * HWPIX + (size_t)hh * WWID + w0) * CC + co;
  cv2[orow]          = f2b(a0);
  cv2[orow + CC]     = f2b(a1);
  cv2[orow + 2 * CC] = f2b(a2);
  cv2[orow + 3 * CC] = f2b(a3);
}

// ---------------- K8: global average pool (sum into pooled, pre-zeroed) ----
__global__ __launch_bounds__(256) void k_pool(const bf16* __restrict__ cv2,
                                              float* __restrict__ pooled) {
  __shared__ float sacc[CC];
  int t = threadIdx.x;
  if (t < CC) sacc[t] = 0.f;
  __syncthreads();
  int b = blockIdx.x >> 7;
  int pc = blockIdx.x & 127;
  const bf16* base = cv2 + (size_t)b * HWPIX * CC + (size_t)pc * 128 * CC;
  for (int it = 0; it < 96; ++it) {
    int e = it * 256 + t;
    atomicAdd(&sacc[e % CC], b2f(base[e]));
  }
  __syncthreads();
  if (t < CC) atomicAdd(&pooled[b * CC + t], sacc[t]);
}

// ---------------- K9: channel attention weights ----------------
__global__ __launch_bounds__(192) void k_ca(const float* __restrict__ pooled,
                                            const float* __restrict__ w1,
                                            const float* __restrict__ b1,
                                            const float* __restrict__ w2,
                                            const float* __restrict__ b2,
                                            float* __restrict__ ca) {
  __shared__ float pld[CC];
  __shared__ float t1[6];
  int t = threadIdx.x, b = blockIdx.x;
  pld[t] = pooled[b * CC + t] * (1.0f / HWPIX);
  __syncthreads();
  if (t < 6) {
    float s = b1[t];
    for (int c = 0; c < CC; ++c) s += pld[c] * w1[c * 6 + t];
    t1[t] = fmaxf(s, 0.f);
  }
  __syncthreads();
  float s = b2[t];
#pragma unroll
  for (int k = 0; k < 6; ++k) s += t1[k] * w2[k * CC + t];
  ca[b * CC + t] = 1.f / (1.f + __expf(-s));
}

// --- K10: LN2 + MLP + residual; folds yf = y + cv2*ca*CONV_SC on the fly ---
__global__ __launch_bounds__(256) void k_mlp(const float* __restrict__ y,
                                             const bf16* __restrict__ cv2,
                                             const float* __restrict__ ca,
                                             const float* __restrict__ g2,
                                             const float* __restrict__ b2,
                                             const float* __restrict__ fw1,
                                             const float* __restrict__ fb1,
                                             const float* __restrict__ fw2,
                                             const float* __restrict__ fb2,
                                             float* __restrict__ out) {
  __shared__ float ynsT[CC * 20];
  __shared__ float hsT[768 * 20];
  int t = threadIdx.x;
  int tok0 = blockIdx.x * 16;
  const float* cab = ca + (tok0 >> 14) * CC;  // all 16 toks in same batch
  int wv = t >> 6, lane = t & 63;
  for (int q = 0; q < 4; ++q) {
    int tk = wv * 4 + q;
    size_t row = (size_t)(tok0 + tk) * CC;
    float v0 = y[row + lane]       + b2f(cv2[row + lane])       * cab[lane]       * CONV_SC;
    float v1 = y[row + lane + 64]  + b2f(cv2[row + lane + 64])  * cab[lane + 64]  * CONV_SC;
    float v2 = y[row + lane + 128] + b2f(cv2[row + lane + 128]) * cab[lane + 128] * CONV_SC;
    float s = v0 + v1 + v2, ss = v0 * v0 + v1 * v1 + v2 * v2;
#pragma unroll
    for (int off = 1; off < 64; off <<= 1) {
      s += __shfl_xor(s, off, 64);
      ss += __shfl_xor(ss, off, 64);
    }
    float mean = s * (1.0f / CC);
    float rstd = rsqrtf(ss * (1.0f / CC) - mean * mean + 1e-5f);
    ynsT[lane * 20 + tk]         = (v0 - mean) * rstd * g2[lane]       + b2[lane];
    ynsT[(lane + 64) * 20 + tk]  = (v1 - mean) * rstd * g2[lane + 64]  + b2[lane + 64];
    ynsT[(lane + 128) * 20 + tk] = (v2 - mean) * rstd * g2[lane + 128] + b2[lane + 128];
  }
  __syncthreads();
  float acc[3][16];
#pragma unroll
  for (int j = 0; j < 3; ++j) {
    float bv = fb1[t + j * 256];
#pragma unroll
    for (int k = 0; k < 16; ++k) acc[j][k] = bv;
  }
  for (int kk = 0; kk < CC; ++kk) {
    float xs16[16];
    const float4* xr = (const float4*)&ynsT[kk * 20];
    *(float4*)&xs16[0] = xr[0]; *(float4*)&xs16[4] = xr[1];
    *(float4*)&xs16[8] = xr[2]; *(float4*)&xs16[12] = xr[3];
    float w0 = fw1[kk * 768 + t];
    float w1 = fw1[kk * 768 + t + 256];
    float w2 = fw1[kk * 768 + t + 512];
#pragma unroll
    for (int k = 0; k < 16; ++k) {
      float xv = xs16[k];
      acc[0][k] += xv * w0; acc[1][k] += xv * w1; acc[2][k] += xv * w2;
    }
  }
#pragma unroll
  for (int j = 0; j < 3; ++j)
    for (int k = 0; k < 16; ++k)
      hsT[(t + j * 256) * 20 + k] = gelu_exact(acc[j][k]);
  __syncthreads();
  if (t < CC) {
    float acc2[16];
    float bv = fb2[t];
#pragma unroll
    for (int k = 0; k < 16; ++k) acc2[k] = bv;
    for (int kk = 0; kk < 768; ++kk) {
      float hs16[16];
      const float4* hr = (const float4*)&hsT[kk * 20];
      *(float4*)&hs16[0] = hr[0]; *(float4*)&hs16[4] = hr[1];
      *(float4*)&hs16[8] = hr[2]; *(float4*)&hs16[12] = hr[3];
      float w = fw2[kk * CC + t];
#pragma unroll
      for (int k = 0; k < 16; ++k) acc2[k] += hs16[k] * w;
    }
#pragma unroll
    for (int k = 0; k < 16; ++k) {
      size_t row = (size_t)(tok0 + k) * CC;
      float yf = y[row + t] + b2f(cv2[row + t]) * cab[t] * CONV_SC;
      out[row + t] = yf + acc2[k];
    }
  }
}

extern "C" void kernel_launch(void* const* d_in, const int* in_sizes, int n_in,
                              void* d_out, int out_size, void* d_ws, size_t ws_size,
                              hipStream_t stream) {
  const float* x      = (const float*)d_in[0];
  const float* qkv_w  = (const float*)d_in[1];
  const float* qkv_b  = (const float*)d_in[2];
  const float* proj_w = (const float*)d_in[3];
  const float* proj_b = (const float*)d_in[4];
  const float* rpb    = (const float*)d_in[5];
  const float* n1w    = (const float*)d_in[6];
  const float* n1b    = (const float*)d_in[7];
  const float* n2w    = (const float*)d_in[8];
  const float* n2b    = (const float*)d_in[9];
  const float* c1w    = (const float*)d_in[10];
  const float* c1b    = (const float*)d_in[11];
  const float* c2w    = (const float*)d_in[12];
  const float* c2b    = (const float*)d_in[13];
  const float* ca1w   = (const float*)d_in[14];
  const float* ca1b   = (const float*)d_in[15];
  const float* ca2w   = (const float*)d_in[16];
  const float* ca2b   = (const float*)d_in[17];
  const float* fc1w   = (const float*)d_in[18];
  const float* fc1b   = (const float*)d_in[19];
  const float* fc2w   = (const float*)d_in[20];
  const float* fc2b   = (const float*)d_in[21];
  const int*   rpi    = (const int*)d_in[22];
  (void)in_sizes; (void)n_in; (void)out_size; (void)ws_size;

  // ---- workspace layout: peak ~211.3 MB (< 256 MiB; R1 crash pinned the cap) ----
  char* wsb = (char*)d_ws;
  bf16*  xn    = (bf16*)(wsb + 0);            // 25,165,824
  float* biasT = (float*)(wsb + 25165824);    //  1,572,864
  bf16*  Qg    = (bf16*)(wsb + 26738688);     // 25,165,824
  bf16*  Kg    = (bf16*)(wsb + 51904512);     // 25,165,824
  bf16*  Vg    = (bf16*)(wsb + 77070336);     // 25,165,824
  bf16*  AO    = (bf16*)(wsb + 102236160);    // 25,165,824
  float* y     = (float*)(wsb + 127401984);   // 50,331,648
  bf16*  cv1   = (bf16*)(wsb + 177733632);    //  8,388,608
  bf16*  cv2   = (bf16*)(wsb + 186122240);    // 25,165,824
  float* pool  = (float*)(wsb + 211288064);   //      3,072
  float* cavec = (float*)(wsb + 211291136);   //      3,072 -> end 211,294,208
  float* out   = (float*)d_out;

  k_ln1<<<TTOT / 4, 256, 0, stream>>>(x, n1w, n1b, xn);
  k_bias<<<NHEAD * NTOK, 256, 0, stream>>>(rpi, rpb, biasT);
  k_qkvg<<<TTOT / 16, 192, 0, stream>>>(xn, qkv_w, qkv_b, Qg, Kg, Vg);
  k_attn<<<BB * 64 * NHEAD, 256, 0, stream>>>(Qg, Kg, Vg, biasT, AO);
  k_proj<<<TTOT / 4, 256, 0, stream>>>(AO, proj_w, proj_b, x, y);
  k_conv1<<<16384, 64, 0, stream>>>(xn, c1w, c1b, cv1);
  k_conv2<<<16384, 192, 0, stream>>>(cv1, c2w, c2b, cv2);
  hipMemsetAsync(pool, 0, BB * CC * sizeof(float), stream);
  k_pool<<<512, 256, 0, stream>>>(cv2, pool);
  k_ca<<<BB, 192, 0, stream>>>(pool, ca1w, ca1b, ca2w, ca2b, cavec);
  k_mlp<<<TTOT / 16, 256, 0, stream>>>(y, cv2, cavec, n2w, n2b, fc1w, fc1b, fc2w, fc2b, out);
}

// Round 8
// 1924.566 us; speedup vs baseline: 2.3803x; 1.5727x over previous
//
#include <hip/hip_runtime.h>
#include <hip/hip_bf16.h>
#include <cstdint>
#include <cstddef>

#define BB 4
#define CC 192
#define NHEAD 6
#define WSZ 16
#define SSH 8
#define NTOK 256
#define HD 32
#define HWPIX 16384
#define TTOT 65536
#define WWID 128
#define SCALE_Q 0.17677669529663687f
#define CONV_SC 0.01f

typedef __hip_bfloat16 bf16;
typedef __attribute__((ext_vector_type(8))) short short8;
typedef __attribute__((ext_vector_type(4))) float float4v;

__device__ __forceinline__ float b2f(bf16 v) { return __bfloat162float(v); }
__device__ __forceinline__ bf16 f2b(float v) { return __float2bfloat16(v); }
__device__ __forceinline__ float lo16(unsigned u) {
  union { unsigned i; float f; } c; c.i = u << 16; return c.f;
}
__device__ __forceinline__ float hi16(unsigned u) {
  union { unsigned i; float f; } c; c.i = u & 0xffff0000u; return c.f;
}
__device__ __forceinline__ unsigned short f2bu(float f) {
  bf16 h = __float2bfloat16(f);
  return *reinterpret_cast<unsigned short*>(&h);
}
__device__ __forceinline__ unsigned pack2(float a, float b) {
  return (unsigned)f2bu(a) | ((unsigned)f2bu(b) << 16);
}
__device__ __forceinline__ float gelu_exact(float x) {
  return 0.5f * x * (1.0f + erff(x * 0.7071067811865475f));
}
__device__ __forceinline__ short8 ld8z(const bf16* p, bool ok) {
  if (ok) return *(const short8*)p;
  short8 z = {0, 0, 0, 0, 0, 0, 0, 0};
  return z;
}

// ---------------- K1: LayerNorm1 (x fp32 -> xn bf16). 1 wave per token -----
__global__ __launch_bounds__(256) void k_ln1(const float* __restrict__ x,
                                             const float* __restrict__ g,
                                             const float* __restrict__ b,
                                             bf16* __restrict__ xn) {
  int wv = threadIdx.x >> 6, lane = threadIdx.x & 63;
  int tok = blockIdx.x * 4 + wv;
  size_t row = (size_t)tok * CC;
  float v0 = x[row + lane], v1 = x[row + lane + 64], v2 = x[row + lane + 128];
  float s = v0 + v1 + v2, ss = v0 * v0 + v1 * v1 + v2 * v2;
#pragma unroll
  for (int off = 1; off < 64; off <<= 1) {
    s += __shfl_xor(s, off, 64);
    ss += __shfl_xor(ss, off, 64);
  }
  float mean = s * (1.0f / CC);
  float rstd = rsqrtf(ss * (1.0f / CC) - mean * mean + 1e-5f);
  xn[row + lane]       = f2b((v0 - mean) * rstd * g[lane]       + b[lane]);
  xn[row + lane + 64]  = f2b((v1 - mean) * rstd * g[lane + 64]  + b[lane + 64]);
  xn[row + lane + 128] = f2b((v2 - mean) * rstd * g[lane + 128] + b[lane + 128]);
}

// ---------------- K2: bias transpose biasT[h][key][query] (fp32) ------------
__global__ __launch_bounds__(256) void k_bias(const int* __restrict__ rpi,
                                              const float* __restrict__ rpb,
                                              float* __restrict__ biasT) {
  int n = threadIdx.x;
  int h = blockIdx.x >> 8;
  int jk = blockIdx.x & 255;
  biasT[(size_t)blockIdx.x * 256 + n] = rpb[rpi[n * 256 + jk] * NHEAD + h];
}

// ------- K2b: conv weight transpose to [tap][oc][ci] bf16 -------------------
__global__ __launch_bounds__(256) void k_wprep(const float* __restrict__ c1w,
                                               const float* __restrict__ c2w,
                                               bf16* __restrict__ wT1,
                                               bf16* __restrict__ wT2) {
  int i = blockIdx.x * 256 + threadIdx.x;   // 0 .. 110591
  {
    int tap = i / (64 * 192); int r = i % (64 * 192);
    int oc = r / 192, ci = r % 192;
    wT1[i] = f2b(c1w[(size_t)(tap * 192 + ci) * 64 + oc]);
  }
  {
    int tap = i / (192 * 64); int r = i % (192 * 64);
    int oc = r / 64, ci = r % 64;
    wT2[i] = f2b(c2w[(size_t)(tap * 64 + ci) * 192 + oc]);
  }
}

// --------- K3: QKV GEMM, writing gathered [win][head][tok][32] layout -------
__global__ __launch_bounds__(192) void k_qkvg(const bf16* __restrict__ xn,
                                              const float* __restrict__ wq,
                                              const float* __restrict__ qb,
                                              bf16* __restrict__ Qg,
                                              bf16* __restrict__ Kg,
                                              bf16* __restrict__ Vg) {
  __shared__ float xsT[CC * 20];
  int t = threadIdx.x;
  int tok0 = blockIdx.x * 16;
  for (int i = 0; i < 16; ++i)
    xsT[t * 20 + i] = b2f(xn[(size_t)(tok0 + i) * CC + t]);
  __syncthreads();
  float acc0[16], acc1[16], acc2[16];
  float b0 = qb[t], b1v = qb[t + 192], b2v = qb[t + 384];
#pragma unroll
  for (int k = 0; k < 16; ++k) { acc0[k] = b0; acc1[k] = b1v; acc2[k] = b2v; }
  for (int kk = 0; kk < CC; ++kk) {
    float xs16[16];
    const float4* xr = (const float4*)&xsT[kk * 20];
    *(float4*)&xs16[0] = xr[0]; *(float4*)&xs16[4] = xr[1];
    *(float4*)&xs16[8] = xr[2]; *(float4*)&xs16[12] = xr[3];
    float w0 = wq[kk * 576 + t];
    float w1 = wq[kk * 576 + t + 192];
    float w2 = wq[kk * 576 + t + 384];
#pragma unroll
    for (int k = 0; k < 16; ++k) {
      float xv = xs16[k];
      acc0[k] += xv * w0; acc1[k] += xv * w1; acc2[k] += xv * w2;
    }
  }
  int hq = t >> 5, dq = t & 31;
  for (int k = 0; k < 16; ++k) {
    int tg = tok0 + k;
    int b = tg >> 14;
    int pix = tg & 16383;
    int gh = pix >> 7, gw = pix & 127;
    int hs = (gh + 120) & 127, wsx = (gw + 120) & 127;  // shifted coords
    int wdx = (b << 6) + ((hs >> 4) << 3) + (wsx >> 4);
    int ndx = ((hs & 15) << 4) + (wsx & 15);
    size_t off = (((size_t)wdx * NHEAD + hq) * NTOK + ndx) * HD + dq;
    Qg[off] = f2b(acc0[k] * SCALE_Q);
    Kg[off] = f2b(acc1[k]);
    Vg[off] = f2b(acc2[k]);
  }
}

#define DOT8(u, b) (q[b+0]*lo16(u.x) + q[b+1]*hi16(u.x) + q[b+2]*lo16(u.y) + q[b+3]*hi16(u.y) + \
                    q[b+4]*lo16(u.z) + q[b+5]*hi16(u.z) + q[b+6]*lo16(u.w) + q[b+7]*hi16(u.w))

#define VMAC(u, b, p)                                 \
  { o[b + 0] += p * lo16(u.x); o[b + 1] += p * hi16(u.x); \
    o[b + 2] += p * lo16(u.y); o[b + 3] += p * hi16(u.y); \
    o[b + 4] += p * lo16(u.z); o[b + 5] += p * hi16(u.z); \
    o[b + 6] += p * lo16(u.w); o[b + 7] += p * hi16(u.w); }

#define VCR(u, b, cr)                                           \
  { o[b + 0] = o[b + 0] * cr + lo16(u.x); o[b + 1] = o[b + 1] * cr + hi16(u.x); \
    o[b + 2] = o[b + 2] * cr + lo16(u.y); o[b + 3] = o[b + 3] * cr + hi16(u.y); \
    o[b + 4] = o[b + 4] * cr + lo16(u.z); o[b + 5] = o[b + 5] * cr + hi16(u.z); \
    o[b + 6] = o[b + 6] * cr + lo16(u.w); o[b + 7] = o[b + 7] * cr + hi16(u.w); }

// --------------- K4: windowed attention, 1 block per (window, head) ---------
__global__ __launch_bounds__(256) void k_attn(const bf16* __restrict__ Qg,
                                              const bf16* __restrict__ Kg,
                                              const bf16* __restrict__ Vg,
                                              const float* __restrict__ biasT,
                                              bf16* __restrict__ AO) {
  __shared__ unsigned short KT[256 * 32];   // 16384 B
  __shared__ unsigned short VT[256 * 32];   // 16384 B
  int n = threadIdx.x;
  int wh = blockIdx.x;
  int wdx = wh / NHEAD;
  int h = wh - wdx * NHEAD;
  int wl = wdx & 63;
  int wr = wl >> 3, wc = wl & 7;
  {
    const uint4* kp = (const uint4*)(Kg + ((size_t)wh * NTOK + n) * HD);
    const uint4* vp = (const uint4*)(Vg + ((size_t)wh * NTOK + n) * HD);
    uint4* kd = (uint4*)&KT[n * 32];
    uint4* vd = (uint4*)&VT[n * 32];
    kd[0] = kp[0]; kd[1] = kp[1]; kd[2] = kp[2]; kd[3] = kp[3];
    vd[0] = vp[0]; vd[1] = vp[1]; vd[2] = vp[2]; vd[3] = vp[3];
  }
  float q[32];
  {
    const uint4* qp = (const uint4*)(Qg + ((size_t)wh * NTOK + n) * HD);
#pragma unroll
    for (int d = 0; d < 4; ++d) {
      uint4 u = qp[d];
      q[d * 8 + 0] = lo16(u.x); q[d * 8 + 1] = hi16(u.x);
      q[d * 8 + 2] = lo16(u.y); q[d * 8 + 3] = hi16(u.y);
      q[d * 8 + 4] = lo16(u.z); q[d * 8 + 5] = hi16(u.z);
      q[d * 8 + 6] = lo16(u.w); q[d * 8 + 7] = hi16(u.w);
    }
  }
  int hs = (wr << 4) + (n >> 4), wsx = (wc << 4) + (n & 15);
  int rid_n = ((hs >= 112) + (hs >= 120)) * 3 + ((wsx >= 112) + (wsx >= 120));
  const float* bbh = biasT + (size_t)h * (NTOK * NTOK) + n;
  __syncthreads();
  float m = -1.0e30f, l = 0.f;
  float o[32];
#pragma unroll
  for (int d = 0; d < 32; ++d) o[d] = 0.f;
  for (int jk = 0; jk < NTOK; ++jk) {
    const uint4* kr = (const uint4*)&KT[jk * 32];
    uint4 k0 = kr[0], k1 = kr[1], k2 = kr[2], k3 = kr[3];
    float s = DOT8(k0, 0) + DOT8(k1, 8) + DOT8(k2, 16) + DOT8(k3, 24);
    s += bbh[jk * 256];
    int hj = (wr << 4) + (jk >> 4), wj = (wc << 4) + (jk & 15);
    int rid_j = ((hj >= 112) + (hj >= 120)) * 3 + ((wj >= 112) + (wj >= 120));
    s += (rid_j != rid_n) ? -100.f : 0.f;
    const uint4* vr = (const uint4*)&VT[jk * 32];
    uint4 v0 = vr[0], v1 = vr[1], v2 = vr[2], v3 = vr[3];
    if (s <= m) {
      float p = __expf(s - m);
      l += p;
      VMAC(v0, 0, p) VMAC(v1, 8, p) VMAC(v2, 16, p) VMAC(v3, 24, p)
    } else {
      float corr = __expf(m - s);
      l = l * corr + 1.f;
      VCR(v0, 0, corr) VCR(v1, 8, corr) VCR(v2, 16, corr) VCR(v3, 24, corr)
      m = s;
    }
  }
  float inv = 1.f / l;
  uint4 pk[4];
#pragma unroll
  for (int i = 0; i < 4; ++i) {
    pk[i].x = pack2(o[i * 8 + 0] * inv, o[i * 8 + 1] * inv);
    pk[i].y = pack2(o[i * 8 + 2] * inv, o[i * 8 + 3] * inv);
    pk[i].z = pack2(o[i * 8 + 4] * inv, o[i * 8 + 5] * inv);
    pk[i].w = pack2(o[i * 8 + 6] * inv, o[i * 8 + 7] * inv);
  }
  uint4* ad = (uint4*)(AO + ((size_t)wdx * NTOK + n) * CC + h * HD);
  ad[0] = pk[0]; ad[1] = pk[1]; ad[2] = pk[2]; ad[3] = pk[3];
}

// ------- K5: proj GEMM + window-reverse + roll-back + x residual (fp32 y) ---
__global__ __launch_bounds__(256) void k_proj(const bf16* __restrict__ AO,
                                              const float* __restrict__ pw,
                                              const float* __restrict__ pb,
                                              const float* __restrict__ x,
                                              float* __restrict__ y) {
  __shared__ float as[4][CC];
  int wv = threadIdx.x >> 6, lane = threadIdx.x & 63;
  int r = blockIdx.x * 4 + wv;
  size_t arow = (size_t)r * CC;
  as[wv][lane]       = b2f(AO[arow + lane]);
  as[wv][lane + 64]  = b2f(AO[arow + lane + 64]);
  as[wv][lane + 128] = b2f(AO[arow + lane + 128]);
  __syncthreads();
  float a0 = pb[lane], a1 = pb[lane + 64], a2 = pb[lane + 128];
  for (int kk = 0; kk < CC; ++kk) {
    float v = as[wv][kk];
    a0 += v * pw[kk * CC + lane];
    a1 += v * pw[kk * CC + lane + 64];
    a2 += v * pw[kk * CC + lane + 128];
  }
  int wdx = r >> 8, n = r & 255;
  int wb = wdx >> 6, wl = wdx & 63;
  int hs = ((wl >> 3) << 4) + (n >> 4);
  int wsx = ((wl & 7) << 4) + (n & 15);
  int gh = (hs + SSH) & 127, gw = (wsx + SSH) & 127;
  size_t drow = ((size_t)wb * HWPIX + (size_t)gh * WWID + gw) * CC;
  y[drow + lane]       = x[drow + lane]       + a0;
  y[drow + lane + 64]  = x[drow + lane + 64]  + a1;
  y[drow + lane + 128] = x[drow + lane + 128] + a2;
}

// ---- K6: conv3x3 192->64 + GELU via MFMA implicit GEMM ---------------------
// grid 1024 (b*128rows*2segs), block 256 (4 waves). Wave w: oc tile w (16 oc),
// 4 M-tiles of 16 px. A/B fragments direct from global (16B/lane), no LDS.
__global__ __launch_bounds__(256) void k_conv1m(const bf16* __restrict__ xn,
                                                const bf16* __restrict__ wT1,
                                                const float* __restrict__ c1b,
                                                bf16* __restrict__ cv1) {
  int bi = blockIdx.x;
  int seg = bi & 1, hh = (bi >> 1) & 127, b = bi >> 8;
  int px0 = seg * 64;
  int wave = threadIdx.x >> 6, lane = threadIdx.x & 63;
  int lm = lane & 15, lq = lane >> 4;
  int oc = wave * 16 + lm;
  float4v acc[4];
#pragma unroll
  for (int t = 0; t < 4; ++t) acc[t] = (float4v){0.f, 0.f, 0.f, 0.f};
#pragma unroll
  for (int tap = 0; tap < 9; ++tap) {
    int kh = tap / 3, kw = tap % 3;
    int gh = hh + kh - 1;
    bool rowok = ((unsigned)gh < 128u);
    const bf16* wrow = wT1 + ((size_t)tap * 64 + oc) * CC + lq * 8;
    const bf16* xrow = xn + ((size_t)b * HWPIX + (size_t)gh * WWID) * CC + lq * 8;
#pragma unroll
    for (int ks = 0; ks < 6; ++ks) {
      short8 bfrag = *(const short8*)(wrow + ks * 32);
#pragma unroll
      for (int t = 0; t < 4; ++t) {
        int px = px0 + t * 16 + lm + kw - 1;
        short8 afrag = ld8z(xrow + (size_t)px * CC + ks * 32,
                            rowok && ((unsigned)px < 128u));
        acc[t] = __builtin_amdgcn_mfma_f32_16x16x32_bf16(afrag, bfrag, acc[t], 0, 0, 0);
      }
    }
  }
  float bias = c1b[oc];
#pragma unroll
  for (int t = 0; t < 4; ++t) {
    int pxb = px0 + t * 16 + lq * 4;
    size_t base = ((size_t)b * HWPIX + (size_t)hh * WWID + pxb) * 64 + oc;
    cv1[base]       = f2b(gelu_exact(acc[t][0] + bias));
    cv1[base + 64]  = f2b(gelu_exact(acc[t][1] + bias));
    cv1[base + 128] = f2b(gelu_exact(acc[t][2] + bias));
    cv1[base + 192] = f2b(gelu_exact(acc[t][3] + bias));
  }
}

// ---- K7: conv3x3 64->192 + bias via MFMA implicit GEMM ---------------------
// grid 1024, block 256. Wave w: 3 oc tiles (w*48..+47), 4 M-tiles of 16 px.
__global__ __launch_bounds__(256) void k_conv2m(const bf16* __restrict__ cv1,
                                                const bf16* __restrict__ wT2,
                                                const float* __restrict__ c2b,
                                                bf16* __restrict__ cv2) {
  int bi = blockIdx.x;
  int seg = bi & 1, hh = (bi >> 1) & 127, b = bi >> 8;
  int px0 = seg * 64;
  int wave = threadIdx.x >> 6, lane = threadIdx.x & 63;
  int lm = lane & 15, lq = lane >> 4;
  float4v acc[3][4];
#pragma unroll
  for (int nt = 0; nt < 3; ++nt)
#pragma unroll
    for (int t = 0; t < 4; ++t) acc[nt][t] = (float4v){0.f, 0.f, 0.f, 0.f};
#pragma unroll
  for (int tap = 0; tap < 9; ++tap) {
    int kh = tap / 3, kw = tap % 3;
    int gh = hh + kh - 1;
    bool rowok = ((unsigned)gh < 128u);
    const bf16* xrow = cv1 + ((size_t)b * HWPIX + (size_t)gh * WWID) * 64 + lq * 8;
#pragma unroll
    for (int ks = 0; ks < 2; ++ks) {
      short8 bfrag[3];
#pragma unroll
      for (int nt = 0; nt < 3; ++nt) {
        int oc = wave * 48 + nt * 16 + lm;
        bfrag[nt] = *(const short8*)(wT2 + ((size_t)tap * 192 + oc) * 64 + ks * 32 + lq * 8);
      }
#pragma unroll
      for (int t = 0; t < 4; ++t) {
        int px = px0 + t * 16 + lm + kw - 1;
        short8 afrag = ld8z(xrow + (size_t)px * 64 + ks * 32,
                            rowok && ((unsigned)px < 128u));
#pragma unroll
        for (int nt = 0; nt < 3; ++nt)
          acc[nt][t] = __builtin_amdgcn_mfma_f32_16x16x32_bf16(afrag, bfrag[nt], acc[nt][t], 0, 0, 0);
      }
    }
  }
#pragma unroll
  for (int nt = 0; nt < 3; ++nt) {
    int oc = wave * 48 + nt * 16 + lm;
    float bias = c2b[oc];
#pragma unroll
    for (int t = 0; t < 4; ++t) {
      int pxb = px0 + t * 16 + lq * 4;
      size_t base = ((size_t)b * HWPIX + (size_t)hh * WWID + pxb) * CC + oc;
      cv2[base]           = f2b(acc[nt][t][0] + bias);
      cv2[base + CC]      = f2b(acc[nt][t][1] + bias);
      cv2[base + 2 * CC]  = f2b(acc[nt][t][2] + bias);
      cv2[base + 3 * CC]  = f2b(acc[nt][t][3] + bias);
    }
  }
}

// ---------------- K8: global average pool (sum into pooled, pre-zeroed) ----
__global__ __launch_bounds__(256) void k_pool(const bf16* __restrict__ cv2,
                                              float* __restrict__ pooled) {
  __shared__ float sacc[CC];
  int t = threadIdx.x;
  if (t < CC) sacc[t] = 0.f;
  __syncthreads();
  int b = blockIdx.x >> 7;
  int pc = blockIdx.x & 127;
  const bf16* base = cv2 + (size_t)b * HWPIX * CC + (size_t)pc * 128 * CC;
  for (int it = 0; it < 96; ++it) {
    int e = it * 256 + t;
    atomicAdd(&sacc[e % CC], b2f(base[e]));
  }
  __syncthreads();
  if (t < CC) atomicAdd(&pooled[b * CC + t], sacc[t]);
}

// ---------------- K9: channel attention weights ----------------
__global__ __launch_bounds__(192) void k_ca(const float* __restrict__ pooled,
                                            const float* __restrict__ w1,
                                            const float* __restrict__ b1,
                                            const float* __restrict__ w2,
                                            const float* __restrict__ b2,
                                            float* __restrict__ ca) {
  __shared__ float pld[CC];
  __shared__ float t1[6];
  int t = threadIdx.x, b = blockIdx.x;
  pld[t] = pooled[b * CC + t] * (1.0f / HWPIX);
  __syncthreads();
  if (t < 6) {
    float s = b1[t];
    for (int c = 0; c < CC; ++c) s += pld[c] * w1[c * 6 + t];
    t1[t] = fmaxf(s, 0.f);
  }
  __syncthreads();
  float s = b2[t];
#pragma unroll
  for (int k = 0; k < 6; ++k) s += t1[k] * w2[k * CC + t];
  ca[b * CC + t] = 1.f / (1.f + __expf(-s));
}

// --- K10: LN2 + MLP + residual; folds yf = y + cv2*ca*CONV_SC on the fly ---
__global__ __launch_bounds__(256) void k_mlp(const float* __restrict__ y,
                                             const bf16* __restrict__ cv2,
                                             const float* __restrict__ ca,
                                             const float* __restrict__ g2,
                                             const float* __restrict__ b2,
                                             const float* __restrict__ fw1,
                                             const float* __restrict__ fb1,
                                             const float* __restrict__ fw2,
                                             const float* __restrict__ fb2,
                                             float* __restrict__ out) {
  __shared__ float ynsT[CC * 20];
  __shared__ float hsT[768 * 20];
  int t = threadIdx.x;
  int tok0 = blockIdx.x * 16;
  const float* cab = ca + (tok0 >> 14) * CC;  // all 16 toks in same batch
  int wv = t >> 6, lane = t & 63;
  for (int q = 0; q < 4; ++q) {
    int tk = wv * 4 + q;
    size_t row = (size_t)(tok0 + tk) * CC;
    float v0 = y[row + lane]       + b2f(cv2[row + lane])       * cab[lane]       * CONV_SC;
    float v1 = y[row + lane + 64]  + b2f(cv2[row + lane + 64])  * cab[lane + 64]  * CONV_SC;
    float v2 = y[row + lane + 128] + b2f(cv2[row + lane + 128]) * cab[lane + 128] * CONV_SC;
    float s = v0 + v1 + v2, ss = v0 * v0 + v1 * v1 + v2 * v2;
#pragma unroll
    for (int off = 1; off < 64; off <<= 1) {
      s += __shfl_xor(s, off, 64);
      ss += __shfl_xor(ss, off, 64);
    }
    float mean = s * (1.0f / CC);
    float rstd = rsqrtf(ss * (1.0f / CC) - mean * mean + 1e-5f);
    ynsT[lane * 20 + tk]         = (v0 - mean) * rstd * g2[lane]       + b2[lane];
    ynsT[(lane + 64) * 20 + tk]  = (v1 - mean) * rstd * g2[lane + 64]  + b2[lane + 64];
    ynsT[(lane + 128) * 20 + tk] = (v2 - mean) * rstd * g2[lane + 128] + b2[lane + 128];
  }
  __syncthreads();
  float acc[3][16];
#pragma unroll
  for (int j = 0; j < 3; ++j) {
    float bv = fb1[t + j * 256];
#pragma unroll
    for (int k = 0; k < 16; ++k) acc[j][k] = bv;
  }
  for (int kk = 0; kk < CC; ++kk) {
    float xs16[16];
    const float4* xr = (const float4*)&ynsT[kk * 20];
    *(float4*)&xs16[0] = xr[0]; *(float4*)&xs16[4] = xr[1];
    *(float4*)&xs16[8] = xr[2]; *(float4*)&xs16[12] = xr[3];
    float w0 = fw1[kk * 768 + t];
    float w1 = fw1[kk * 768 + t + 256];
    float w2 = fw1[kk * 768 + t + 512];
#pragma unroll
    for (int k = 0; k < 16; ++k) {
      float xv = xs16[k];
      acc[0][k] += xv * w0; acc[1][k] += xv * w1; acc[2][k] += xv * w2;
    }
  }
#pragma unroll
  for (int j = 0; j < 3; ++j)
    for (int k = 0; k < 16; ++k)
      hsT[(t + j * 256) * 20 + k] = gelu_exact(acc[j][k]);
  __syncthreads();
  if (t < CC) {
    float acc2[16];
    float bv = fb2[t];
#pragma unroll
    for (int k = 0; k < 16; ++k) acc2[k] = bv;
    for (int kk = 0; kk < 768; ++kk) {
      float hs16[16];
      const float4* hr = (const float4*)&hsT[kk * 20];
      *(float4*)&hs16[0] = hr[0]; *(float4*)&hs16[4] = hr[1];
      *(float4*)&hs16[8] = hr[2]; *(float4*)&hs16[12] = hr[3];
      float w = fw2[kk * CC + t];
#pragma unroll
      for (int k = 0; k < 16; ++k) acc2[k] += hs16[k] * w;
    }
#pragma unroll
    for (int k = 0; k < 16; ++k) {
      size_t row = (size_t)(tok0 + k) * CC;
      float yf = y[row + t] + b2f(cv2[row + t]) * cab[t] * CONV_SC;
      out[row + t] = yf + acc2[k];
    }
  }
}

extern "C" void kernel_launch(void* const* d_in, const int* in_sizes, int n_in,
                              void* d_out, int out_size, void* d_ws, size_t ws_size,
                              hipStream_t stream) {
  const float* x      = (const float*)d_in[0];
  const float* qkv_w  = (const float*)d_in[1];
  const float* qkv_b  = (const float*)d_in[2];
  const float* proj_w = (const float*)d_in[3];
  const float* proj_b = (const float*)d_in[4];
  const float* rpb    = (const float*)d_in[5];
  const float* n1w    = (const float*)d_in[6];
  const float* n1b    = (const float*)d_in[7];
  const float* n2w    = (const float*)d_in[8];
  const float* n2b    = (const float*)d_in[9];
  const float* c1w    = (const float*)d_in[10];
  const float* c1b    = (const float*)d_in[11];
  const float* c2w    = (const float*)d_in[12];
  const float* c2b    = (const float*)d_in[13];
  const float* ca1w   = (const float*)d_in[14];
  const float* ca1b   = (const float*)d_in[15];
  const float* ca2w   = (const float*)d_in[16];
  const float* ca2b   = (const float*)d_in[17];
  const float* fc1w   = (const float*)d_in[18];
  const float* fc1b   = (const float*)d_in[19];
  const float* fc2w   = (const float*)d_in[20];
  const float* fc2b   = (const float*)d_in[21];
  const int*   rpi    = (const int*)d_in[22];
  (void)in_sizes; (void)n_in; (void)out_size; (void)ws_size;

  // ---- workspace layout: peak ~211.7 MB (< 256 MiB) ----
  char* wsb = (char*)d_ws;
  bf16*  xn    = (bf16*)(wsb + 0);            // 25,165,824
  float* biasT = (float*)(wsb + 25165824);    //  1,572,864
  bf16*  Qg    = (bf16*)(wsb + 26738688);     // 25,165,824
  bf16*  Kg    = (bf16*)(wsb + 51904512);     // 25,165,824
  bf16*  Vg    = (bf16*)(wsb + 77070336);     // 25,165,824
  bf16*  AO    = (bf16*)(wsb + 102236160);    // 25,165,824
  float* y     = (float*)(wsb + 127401984);   // 50,331,648
  bf16*  cv1   = (bf16*)(wsb + 177733632);    //  8,388,608
  bf16*  cv2   = (bf16*)(wsb + 186122240);    // 25,165,824
  float* pool  = (float*)(wsb + 211288064);   //      3,072
  float* cavec = (float*)(wsb + 211291136);   //      3,072
  bf16*  wT1   = (bf16*)(wsb + 211294208);    //    221,184  [9][64][192]
  bf16*  wT2   = (bf16*)(wsb + 211515392);    //    221,184  [9][192][64]
  float* out   = (float*)d_out;               // end 211,736,576

  k_ln1<<<TTOT / 4, 256, 0, stream>>>(x, n1w, n1b, xn);
  k_bias<<<NHEAD * NTOK, 256, 0, stream>>>(rpi, rpb, biasT);
  k_wprep<<<432, 256, 0, stream>>>(c1w, c2w, wT1, wT2);
  k_qkvg<<<TTOT / 16, 192, 0, stream>>>(xn, qkv_w, qkv_b, Qg, Kg, Vg);
  k_attn<<<BB * 64 * NHEAD, 256, 0, stream>>>(Qg, Kg, Vg, biasT, AO);
  k_proj<<<TTOT / 4, 256, 0, stream>>>(AO, proj_w, proj_b, x, y);
  k_conv1m<<<1024, 256, 0, stream>>>(xn, wT1, c1b, cv1);
  k_conv2m<<<1024, 256, 0, stream>>>(cv1, wT2, c2b, cv2);
  hipMemsetAsync(pool, 0, BB * CC * sizeof(float), stream);
  k_pool<<<512, 256, 0, stream>>>(cv2, pool);
  k_ca<<<BB, 192, 0, stream>>>(pool, ca1w, ca1b, ca2w, ca2b, cavec);
  k_mlp<<<TTOT / 16, 256, 0, stream>>>(y, cv2, cavec, n2w, n2b, fc1w, fc1b, fc2w, fc2b, out);
}

// Round 9
// 1577.469 us; speedup vs baseline: 2.9041x; 1.2200x over previous
//
#include <hip/hip_runtime.h>
#include <hip/hip_bf16.h>
#include <cstdint>
#include <cstddef>

#define BB 4
#define CC 192
#define NHEAD 6
#define WSZ 16
#define SSH 8
#define NTOK 256
#define HD 32
#define HWPIX 16384
#define TTOT 65536
#define WWID 128
#define SCALE_Q 0.17677669529663687f
#define CONV_SC 0.01f

typedef __hip_bfloat16 bf16;
typedef __attribute__((ext_vector_type(8))) short short8;
typedef __attribute__((ext_vector_type(4))) float float4v;

__device__ __forceinline__ float b2f(bf16 v) { return __bfloat162float(v); }
__device__ __forceinline__ bf16 f2b(float v) { return __float2bfloat16(v); }
__device__ __forceinline__ float lo16(unsigned u) {
  union { unsigned i; float f; } c; c.i = u << 16; return c.f;
}
__device__ __forceinline__ float hi16(unsigned u) {
  union { unsigned i; float f; } c; c.i = u & 0xffff0000u; return c.f;
}
__device__ __forceinline__ unsigned short f2bu(float f) {
  bf16 h = __float2bfloat16(f);
  return *reinterpret_cast<unsigned short*>(&h);
}
__device__ __forceinline__ unsigned pack2(float a, float b) {
  return (unsigned)f2bu(a) | ((unsigned)f2bu(b) << 16);
}
__device__ __forceinline__ float gelu_exact(float x) {
  return 0.5f * x * (1.0f + erff(x * 0.7071067811865475f));
}
__device__ __forceinline__ short8 ld8z(const bf16* p, bool ok) {
  if (ok) return *(const short8*)p;
  short8 z = {0, 0, 0, 0, 0, 0, 0, 0};
  return z;
}

// ---------------- K1: LayerNorm1 (x fp32 -> xn bf16). 1 wave per token -----
__global__ __launch_bounds__(256) void k_ln1(const float* __restrict__ x,
                                             const float* __restrict__ g,
                                             const float* __restrict__ b,
                                             bf16* __restrict__ xn) {
  int wv = threadIdx.x >> 6, lane = threadIdx.x & 63;
  int tok = blockIdx.x * 4 + wv;
  size_t row = (size_t)tok * CC;
  float v0 = x[row + lane], v1 = x[row + lane + 64], v2 = x[row + lane + 128];
  float s = v0 + v1 + v2, ss = v0 * v0 + v1 * v1 + v2 * v2;
#pragma unroll
  for (int off = 1; off < 64; off <<= 1) {
    s += __shfl_xor(s, off, 64);
    ss += __shfl_xor(ss, off, 64);
  }
  float mean = s * (1.0f / CC);
  float rstd = rsqrtf(ss * (1.0f / CC) - mean * mean + 1e-5f);
  xn[row + lane]       = f2b((v0 - mean) * rstd * g[lane]       + b[lane]);
  xn[row + lane + 64]  = f2b((v1 - mean) * rstd * g[lane + 64]  + b[lane + 64]);
  xn[row + lane + 128] = f2b((v2 - mean) * rstd * g[lane + 128] + b[lane + 128]);
}

// ---------------- K2: bias transpose biasT[h][key][query] (fp32) ------------
__global__ __launch_bounds__(256) void k_bias(const int* __restrict__ rpi,
                                              const float* __restrict__ rpb,
                                              float* __restrict__ biasT) {
  int n = threadIdx.x;
  int h = blockIdx.x >> 8;
  int jk = blockIdx.x & 255;
  biasT[(size_t)blockIdx.x * 256 + n] = rpb[rpi[n * 256 + jk] * NHEAD + h];
}

// ------- K2b: conv weight transpose to [tap][oc][ci] bf16 -------------------
__global__ __launch_bounds__(256) void k_wprep(const float* __restrict__ c1w,
                                               const float* __restrict__ c2w,
                                               bf16* __restrict__ wT1,
                                               bf16* __restrict__ wT2) {
  int i = blockIdx.x * 256 + threadIdx.x;   // 0 .. 110591
  {
    int tap = i / (64 * 192); int r = i % (64 * 192);
    int oc = r / 192, ci = r % 192;
    wT1[i] = f2b(c1w[(size_t)(tap * 192 + ci) * 64 + oc]);
  }
  {
    int tap = i / (192 * 64); int r = i % (192 * 64);
    int oc = r / 64, ci = r % 64;
    wT2[i] = f2b(c2w[(size_t)(tap * 64 + ci) * 192 + oc]);
  }
}

// ------- K2c: MLP weight transpose to n-major bf16 --------------------------
__global__ __launch_bounds__(256) void k_wprep2(const float* __restrict__ fc1w,
                                                const float* __restrict__ fc2w,
                                                bf16* __restrict__ wF1,
                                                bf16* __restrict__ wF2) {
  int i = blockIdx.x * 256 + threadIdx.x;   // 0 .. 147455
  {
    int n = i / 192, k = i % 192;           // wF1[n][k], n<768 k<192
    wF1[i] = f2b(fc1w[(size_t)k * 768 + n]);
  }
  {
    int n = i / 768, k = i % 768;           // wF2[n][k], n<192 k<768
    wF2[i] = f2b(fc2w[(size_t)k * 192 + n]);
  }
}

// --------- K3: QKV GEMM, writing gathered [win][head][tok][32] layout -------
__global__ __launch_bounds__(192) void k_qkvg(const bf16* __restrict__ xn,
                                              const float* __restrict__ wq,
                                              const float* __restrict__ qb,
                                              bf16* __restrict__ Qg,
                                              bf16* __restrict__ Kg,
                                              bf16* __restrict__ Vg) {
  __shared__ float xsT[CC * 20];
  int t = threadIdx.x;
  int tok0 = blockIdx.x * 16;
  for (int i = 0; i < 16; ++i)
    xsT[t * 20 + i] = b2f(xn[(size_t)(tok0 + i) * CC + t]);
  __syncthreads();
  float acc0[16], acc1[16], acc2[16];
  float b0 = qb[t], b1v = qb[t + 192], b2v = qb[t + 384];
#pragma unroll
  for (int k = 0; k < 16; ++k) { acc0[k] = b0; acc1[k] = b1v; acc2[k] = b2v; }
  for (int kk = 0; kk < CC; ++kk) {
    float xs16[16];
    const float4* xr = (const float4*)&xsT[kk * 20];
    *(float4*)&xs16[0] = xr[0]; *(float4*)&xs16[4] = xr[1];
    *(float4*)&xs16[8] = xr[2]; *(float4*)&xs16[12] = xr[3];
    float w0 = wq[kk * 576 + t];
    float w1 = wq[kk * 576 + t + 192];
    float w2 = wq[kk * 576 + t + 384];
#pragma unroll
    for (int k = 0; k < 16; ++k) {
      float xv = xs16[k];
      acc0[k] += xv * w0; acc1[k] += xv * w1; acc2[k] += xv * w2;
    }
  }
  int hq = t >> 5, dq = t & 31;
  for (int k = 0; k < 16; ++k) {
    int tg = tok0 + k;
    int b = tg >> 14;
    int pix = tg & 16383;
    int gh = pix >> 7, gw = pix & 127;
    int hs = (gh + 120) & 127, wsx = (gw + 120) & 127;  // shifted coords
    int wdx = (b << 6) + ((hs >> 4) << 3) + (wsx >> 4);
    int ndx = ((hs & 15) << 4) + (wsx & 15);
    size_t off = (((size_t)wdx * NHEAD + hq) * NTOK + ndx) * HD + dq;
    Qg[off] = f2b(acc0[k] * SCALE_Q);
    Kg[off] = f2b(acc1[k]);
    Vg[off] = f2b(acc2[k]);
  }
}

#define DOT8(u, b) (q[b+0]*lo16(u.x) + q[b+1]*hi16(u.x) + q[b+2]*lo16(u.y) + q[b+3]*hi16(u.y) + \
                    q[b+4]*lo16(u.z) + q[b+5]*hi16(u.z) + q[b+6]*lo16(u.w) + q[b+7]*hi16(u.w))

#define VMAC(u, b, p)                                 \
  { o[b + 0] += p * lo16(u.x); o[b + 1] += p * hi16(u.x); \
    o[b + 2] += p * lo16(u.y); o[b + 3] += p * hi16(u.y); \
    o[b + 4] += p * lo16(u.z); o[b + 5] += p * hi16(u.z); \
    o[b + 6] += p * lo16(u.w); o[b + 7] += p * hi16(u.w); }

#define VCR(u, b, cr)                                           \
  { o[b + 0] = o[b + 0] * cr + lo16(u.x); o[b + 1] = o[b + 1] * cr + hi16(u.x); \
    o[b + 2] = o[b + 2] * cr + lo16(u.y); o[b + 3] = o[b + 3] * cr + hi16(u.y); \
    o[b + 4] = o[b + 4] * cr + lo16(u.z); o[b + 5] = o[b + 5] * cr + hi16(u.z); \
    o[b + 6] = o[b + 6] * cr + lo16(u.w); o[b + 7] = o[b + 7] * cr + hi16(u.w); }

// --------------- K4: windowed attention, 1 block per (window, head) ---------
__global__ __launch_bounds__(256) void k_attn(const bf16* __restrict__ Qg,
                                              const bf16* __restrict__ Kg,
                                              const bf16* __restrict__ Vg,
                                              const float* __restrict__ biasT,
                                              bf16* __restrict__ AO) {
  __shared__ unsigned short KT[256 * 32];   // 16384 B
  __shared__ unsigned short VT[256 * 32];   // 16384 B
  int n = threadIdx.x;
  int wh = blockIdx.x;
  int wdx = wh / NHEAD;
  int h = wh - wdx * NHEAD;
  int wl = wdx & 63;
  int wr = wl >> 3, wc = wl & 7;
  {
    const uint4* kp = (const uint4*)(Kg + ((size_t)wh * NTOK + n) * HD);
    const uint4* vp = (const uint4*)(Vg + ((size_t)wh * NTOK + n) * HD);
    uint4* kd = (uint4*)&KT[n * 32];
    uint4* vd = (uint4*)&VT[n * 32];
    kd[0] = kp[0]; kd[1] = kp[1]; kd[2] = kp[2]; kd[3] = kp[3];
    vd[0] = vp[0]; vd[1] = vp[1]; vd[2] = vp[2]; vd[3] = vp[3];
  }
  float q[32];
  {
    const uint4* qp = (const uint4*)(Qg + ((size_t)wh * NTOK + n) * HD);
#pragma unroll
    for (int d = 0; d < 4; ++d) {
      uint4 u = qp[d];
      q[d * 8 + 0] = lo16(u.x); q[d * 8 + 1] = hi16(u.x);
      q[d * 8 + 2] = lo16(u.y); q[d * 8 + 3] = hi16(u.y);
      q[d * 8 + 4] = lo16(u.z); q[d * 8 + 5] = hi16(u.z);
      q[d * 8 + 6] = lo16(u.w); q[d * 8 + 7] = hi16(u.w);
    }
  }
  int hs = (wr << 4) + (n >> 4), wsx = (wc << 4) + (n & 15);
  int rid_n = ((hs >= 112) + (hs >= 120)) * 3 + ((wsx >= 112) + (wsx >= 120));
  const float* bbh = biasT + (size_t)h * (NTOK * NTOK) + n;
  __syncthreads();
  float m = -1.0e30f, l = 0.f;
  float o[32];
#pragma unroll
  for (int d = 0; d < 32; ++d) o[d] = 0.f;
  for (int jk = 0; jk < NTOK; ++jk) {
    const uint4* kr = (const uint4*)&KT[jk * 32];
    uint4 k0 = kr[0], k1 = kr[1], k2 = kr[2], k3 = kr[3];
    float s = DOT8(k0, 0) + DOT8(k1, 8) + DOT8(k2, 16) + DOT8(k3, 24);
    s += bbh[jk * 256];
    int hj = (wr << 4) + (jk >> 4), wj = (wc << 4) + (jk & 15);
    int rid_j = ((hj >= 112) + (hj >= 120)) * 3 + ((wj >= 112) + (wj >= 120));
    s += (rid_j != rid_n) ? -100.f : 0.f;
    const uint4* vr = (const uint4*)&VT[jk * 32];
    uint4 v0 = vr[0], v1 = vr[1], v2 = vr[2], v3 = vr[3];
    if (s <= m) {
      float p = __expf(s - m);
      l += p;
      VMAC(v0, 0, p) VMAC(v1, 8, p) VMAC(v2, 16, p) VMAC(v3, 24, p)
    } else {
      float corr = __expf(m - s);
      l = l * corr + 1.f;
      VCR(v0, 0, corr) VCR(v1, 8, corr) VCR(v2, 16, corr) VCR(v3, 24, corr)
      m = s;
    }
  }
  float inv = 1.f / l;
  uint4 pk[4];
#pragma unroll
  for (int i = 0; i < 4; ++i) {
    pk[i].x = pack2(o[i * 8 + 0] * inv, o[i * 8 + 1] * inv);
    pk[i].y = pack2(o[i * 8 + 2] * inv, o[i * 8 + 3] * inv);
    pk[i].z = pack2(o[i * 8 + 4] * inv, o[i * 8 + 5] * inv);
    pk[i].w = pack2(o[i * 8 + 6] * inv, o[i * 8 + 7] * inv);
  }
  uint4* ad = (uint4*)(AO + ((size_t)wdx * NTOK + n) * CC + h * HD);
  ad[0] = pk[0]; ad[1] = pk[1]; ad[2] = pk[2]; ad[3] = pk[3];
}

// ------- K5: proj GEMM + window-reverse + roll-back + x residual (fp32 y) ---
__global__ __launch_bounds__(256) void k_proj(const bf16* __restrict__ AO,
                                              const float* __restrict__ pw,
                                              const float* __restrict__ pb,
                                              const float* __restrict__ x,
                                              float* __restrict__ y) {
  __shared__ float as[4][CC];
  int wv = threadIdx.x >> 6, lane = threadIdx.x & 63;
  int r = blockIdx.x * 4 + wv;
  size_t arow = (size_t)r * CC;
  as[wv][lane]       = b2f(AO[arow + lane]);
  as[wv][lane + 64]  = b2f(AO[arow + lane + 64]);
  as[wv][lane + 128] = b2f(AO[arow + lane + 128]);
  __syncthreads();
  float a0 = pb[lane], a1 = pb[lane + 64], a2 = pb[lane + 128];
  for (int kk = 0; kk < CC; ++kk) {
    float v = as[wv][kk];
    a0 += v * pw[kk * CC + lane];
    a1 += v * pw[kk * CC + lane + 64];
    a2 += v * pw[kk * CC + lane + 128];
  }
  int wdx = r >> 8, n = r & 255;
  int wb = wdx >> 6, wl = wdx & 63;
  int hs = ((wl >> 3) << 4) + (n >> 4);
  int wsx = ((wl & 7) << 4) + (n & 15);
  int gh = (hs + SSH) & 127, gw = (wsx + SSH) & 127;
  size_t drow = ((size_t)wb * HWPIX + (size_t)gh * WWID + gw) * CC;
  y[drow + lane]       = x[drow + lane]       + a0;
  y[drow + lane + 64]  = x[drow + lane + 64]  + a1;
  y[drow + lane + 128] = x[drow + lane + 128] + a2;
}

// ---- K6: conv3x3 192->64 + GELU via MFMA implicit GEMM ---------------------
__global__ __launch_bounds__(256) void k_conv1m(const bf16* __restrict__ xn,
                                                const bf16* __restrict__ wT1,
                                                const float* __restrict__ c1b,
                                                bf16* __restrict__ cv1) {
  int bi = blockIdx.x;
  int seg = bi & 1, hh = (bi >> 1) & 127, b = bi >> 8;
  int px0 = seg * 64;
  int wave = threadIdx.x >> 6, lane = threadIdx.x & 63;
  int lm = lane & 15, lq = lane >> 4;
  int oc = wave * 16 + lm;
  float4v acc[4];
#pragma unroll
  for (int t = 0; t < 4; ++t) acc[t] = (float4v){0.f, 0.f, 0.f, 0.f};
#pragma unroll
  for (int tap = 0; tap < 9; ++tap) {
    int kh = tap / 3, kw = tap % 3;
    int gh = hh + kh - 1;
    bool rowok = ((unsigned)gh < 128u);
    const bf16* wrow = wT1 + ((size_t)tap * 64 + oc) * CC + lq * 8;
    const bf16* xrow = xn + ((size_t)b * HWPIX + (size_t)gh * WWID) * CC + lq * 8;
#pragma unroll
    for (int ks = 0; ks < 6; ++ks) {
      short8 bfrag = *(const short8*)(wrow + ks * 32);
#pragma unroll
      for (int t = 0; t < 4; ++t) {
        int px = px0 + t * 16 + lm + kw - 1;
        short8 afrag = ld8z(xrow + (size_t)px * CC + ks * 32,
                            rowok && ((unsigned)px < 128u));
        acc[t] = __builtin_amdgcn_mfma_f32_16x16x32_bf16(afrag, bfrag, acc[t], 0, 0, 0);
      }
    }
  }
  float bias = c1b[oc];
#pragma unroll
  for (int t = 0; t < 4; ++t) {
    int pxb = px0 + t * 16 + lq * 4;
    size_t base = ((size_t)b * HWPIX + (size_t)hh * WWID + pxb) * 64 + oc;
    cv1[base]       = f2b(gelu_exact(acc[t][0] + bias));
    cv1[base + 64]  = f2b(gelu_exact(acc[t][1] + bias));
    cv1[base + 128] = f2b(gelu_exact(acc[t][2] + bias));
    cv1[base + 192] = f2b(gelu_exact(acc[t][3] + bias));
  }
}

// ---- K7: conv3x3 64->192 + bias via MFMA implicit GEMM ---------------------
__global__ __launch_bounds__(256) void k_conv2m(const bf16* __restrict__ cv1,
                                                const bf16* __restrict__ wT2,
                                                const float* __restrict__ c2b,
                                                bf16* __restrict__ cv2) {
  int bi = blockIdx.x;
  int seg = bi & 1, hh = (bi >> 1) & 127, b = bi >> 8;
  int px0 = seg * 64;
  int wave = threadIdx.x >> 6, lane = threadIdx.x & 63;
  int lm = lane & 15, lq = lane >> 4;
  float4v acc[3][4];
#pragma unroll
  for (int nt = 0; nt < 3; ++nt)
#pragma unroll
    for (int t = 0; t < 4; ++t) acc[nt][t] = (float4v){0.f, 0.f, 0.f, 0.f};
#pragma unroll
  for (int tap = 0; tap < 9; ++tap) {
    int kh = tap / 3, kw = tap % 3;
    int gh = hh + kh - 1;
    bool rowok = ((unsigned)gh < 128u);
    const bf16* xrow = cv1 + ((size_t)b * HWPIX + (size_t)gh * WWID) * 64 + lq * 8;
#pragma unroll
    for (int ks = 0; ks < 2; ++ks) {
      short8 bfrag[3];
#pragma unroll
      for (int nt = 0; nt < 3; ++nt) {
        int oc = wave * 48 + nt * 16 + lm;
        bfrag[nt] = *(const short8*)(wT2 + ((size_t)tap * 192 + oc) * 64 + ks * 32 + lq * 8);
      }
#pragma unroll
      for (int t = 0; t < 4; ++t) {
        int px = px0 + t * 16 + lm + kw - 1;
        short8 afrag = ld8z(xrow + (size_t)px * 64 + ks * 32,
                            rowok && ((unsigned)px < 128u));
#pragma unroll
        for (int nt = 0; nt < 3; ++nt)
          acc[nt][t] = __builtin_amdgcn_mfma_f32_16x16x32_bf16(afrag, bfrag[nt], acc[nt][t], 0, 0, 0);
      }
    }
  }
#pragma unroll
  for (int nt = 0; nt < 3; ++nt) {
    int oc = wave * 48 + nt * 16 + lm;
    float bias = c2b[oc];
#pragma unroll
    for (int t = 0; t < 4; ++t) {
      int pxb = px0 + t * 16 + lq * 4;
      size_t base = ((size_t)b * HWPIX + (size_t)hh * WWID + pxb) * CC + oc;
      cv2[base]           = f2b(acc[nt][t][0] + bias);
      cv2[base + CC]      = f2b(acc[nt][t][1] + bias);
      cv2[base + 2 * CC]  = f2b(acc[nt][t][2] + bias);
      cv2[base + 3 * CC]  = f2b(acc[nt][t][3] + bias);
    }
  }
}

// ---------------- K8: global average pool (sum into pooled, pre-zeroed) ----
__global__ __launch_bounds__(256) void k_pool(const bf16* __restrict__ cv2,
                                              float* __restrict__ pooled) {
  __shared__ float sacc[CC];
  int t = threadIdx.x;
  if (t < CC) sacc[t] = 0.f;
  __syncthreads();
  int b = blockIdx.x >> 7;
  int pc = blockIdx.x & 127;
  const bf16* base = cv2 + (size_t)b * HWPIX * CC + (size_t)pc * 128 * CC;
  for (int it = 0; it < 96; ++it) {
    int e = it * 256 + t;
    atomicAdd(&sacc[e % CC], b2f(base[e]));
  }
  __syncthreads();
  if (t < CC) atomicAdd(&pooled[b * CC + t], sacc[t]);
}

// ---------------- K9: channel attention weights ----------------
__global__ __launch_bounds__(192) void k_ca(const float* __restrict__ pooled,
                                            const float* __restrict__ w1,
                                            const float* __restrict__ b1,
                                            const float* __restrict__ w2,
                                            const float* __restrict__ b2,
                                            float* __restrict__ ca) {
  __shared__ float pld[CC];
  __shared__ float t1[6];
  int t = threadIdx.x, b = blockIdx.x;
  pld[t] = pooled[b * CC + t] * (1.0f / HWPIX);
  __syncthreads();
  if (t < 6) {
    float s = b1[t];
    for (int c = 0; c < CC; ++c) s += pld[c] * w1[c * 6 + t];
    t1[t] = fmaxf(s, 0.f);
  }
  __syncthreads();
  float s = b2[t];
#pragma unroll
  for (int k = 0; k < 6; ++k) s += t1[k] * w2[k * CC + t];
  ca[b * CC + t] = 1.f / (1.f + __expf(-s));
}

// --- K10: LN2 with conv-branch fold: yn = LN(y + cv2*ca*0.01) bf16 ---------
__global__ __launch_bounds__(256) void k_ln2(const float* __restrict__ y,
                                             const bf16* __restrict__ cv2,
                                             const float* __restrict__ ca,
                                             const float* __restrict__ g2,
                                             const float* __restrict__ b2,
                                             bf16* __restrict__ yn) {
  int wv = threadIdx.x >> 6, lane = threadIdx.x & 63;
  int tok = blockIdx.x * 4 + wv;
  const float* cab = ca + (tok >> 14) * CC;
  size_t row = (size_t)tok * CC;
  float v0 = y[row + lane]       + b2f(cv2[row + lane])       * cab[lane]       * CONV_SC;
  float v1 = y[row + lane + 64]  + b2f(cv2[row + lane + 64])  * cab[lane + 64]  * CONV_SC;
  float v2 = y[row + lane + 128] + b2f(cv2[row + lane + 128]) * cab[lane + 128] * CONV_SC;
  float s = v0 + v1 + v2, ss = v0 * v0 + v1 * v1 + v2 * v2;
#pragma unroll
  for (int off = 1; off < 64; off <<= 1) {
    s += __shfl_xor(s, off, 64);
    ss += __shfl_xor(ss, off, 64);
  }
  float mean = s * (1.0f / CC);
  float rstd = rsqrtf(ss * (1.0f / CC) - mean * mean + 1e-5f);
  yn[row + lane]       = f2b((v0 - mean) * rstd * g2[lane]       + b2[lane]);
  yn[row + lane + 64]  = f2b((v1 - mean) * rstd * g2[lane + 64]  + b2[lane + 64]);
  yn[row + lane + 128] = f2b((v2 - mean) * rstd * g2[lane + 128] + b2[lane + 128]);
}

// --- K11: fc1 GEMM (K=192, N=768) + GELU via MFMA -> h bf16 -----------------
// grid TTOT/16, block 256 (4 waves). Wave w covers cols w*192..+191 (12 tiles).
__global__ __launch_bounds__(256) void k_fc1(const bf16* __restrict__ yn,
                                             const bf16* __restrict__ wF1,
                                             const float* __restrict__ fb1,
                                             bf16* __restrict__ h) {
  int tok0 = blockIdx.x * 16;
  int wave = threadIdx.x >> 6, lane = threadIdx.x & 63;
  int lm = lane & 15, lq = lane >> 4;
  const bf16* arow = yn + (size_t)(tok0 + lm) * CC + lq * 8;
  float4v acc[12];
#pragma unroll
  for (int nt = 0; nt < 12; ++nt) acc[nt] = (float4v){0.f, 0.f, 0.f, 0.f};
#pragma unroll
  for (int ks = 0; ks < 6; ++ks) {
    short8 afrag = *(const short8*)(arow + ks * 32);
#pragma unroll
    for (int nt = 0; nt < 12; ++nt) {
      int col = wave * 192 + nt * 16 + lm;
      short8 bfrag = *(const short8*)(wF1 + (size_t)col * CC + ks * 32 + lq * 8);
      acc[nt] = __builtin_amdgcn_mfma_f32_16x16x32_bf16(afrag, bfrag, acc[nt], 0, 0, 0);
    }
  }
#pragma unroll
  for (int nt = 0; nt < 12; ++nt) {
    int col = wave * 192 + nt * 16 + lm;
    float bias = fb1[col];
    size_t base = (size_t)(tok0 + lq * 4) * 768 + col;
    h[base]         = f2b(gelu_exact(acc[nt][0] + bias));
    h[base + 768]   = f2b(gelu_exact(acc[nt][1] + bias));
    h[base + 1536]  = f2b(gelu_exact(acc[nt][2] + bias));
    h[base + 2304]  = f2b(gelu_exact(acc[nt][3] + bias));
  }
}

// --- K12: fc2 GEMM (K=768, N=192) + residual epilogue via MFMA --------------
// grid TTOT/16, block 256 (4 waves). Wave w covers cols w*48..+47 (3 tiles).
// Epilogue recomputes yf = y + cv2*ca*0.01 in fp32 and writes out = yf+fc2+b.
__global__ __launch_bounds__(256) void k_fc2(const bf16* __restrict__ h,
                                             const bf16* __restrict__ wF2,
                                             const float* __restrict__ fb2,
                                             const float* __restrict__ y,
                                             const bf16* __restrict__ cv2,
                                             const float* __restrict__ ca,
                                             float* __restrict__ out) {
  int tok0 = blockIdx.x * 16;
  int wave = threadIdx.x >> 6, lane = threadIdx.x & 63;
  int lm = lane & 15, lq = lane >> 4;
  const bf16* arow = h + (size_t)(tok0 + lm) * 768 + lq * 8;
  float4v acc[3];
#pragma unroll
  for (int nt = 0; nt < 3; ++nt) acc[nt] = (float4v){0.f, 0.f, 0.f, 0.f};
#pragma unroll
  for (int ks = 0; ks < 24; ++ks) {
    short8 afrag = *(const short8*)(arow + ks * 32);
#pragma unroll
    for (int nt = 0; nt < 3; ++nt) {
      int col = wave * 48 + nt * 16 + lm;
      short8 bfrag = *(const short8*)(wF2 + (size_t)col * 768 + ks * 32 + lq * 8);
      acc[nt] = __builtin_amdgcn_mfma_f32_16x16x32_bf16(afrag, bfrag, acc[nt], 0, 0, 0);
    }
  }
  const float* cab = ca + (tok0 >> 14) * CC;
#pragma unroll
  for (int nt = 0; nt < 3; ++nt) {
    int col = wave * 48 + nt * 16 + lm;
    float bias = fb2[col];
#pragma unroll
    for (int reg = 0; reg < 4; ++reg) {
      int tok = tok0 + lq * 4 + reg;
      size_t idx = (size_t)tok * CC + col;
      float yf = y[idx] + b2f(cv2[idx]) * cab[col] * CONV_SC;
      out[idx] = yf + acc[nt][reg] + bias;
    }
  }
}

extern "C" void kernel_launch(void* const* d_in, const int* in_sizes, int n_in,
                              void* d_out, int out_size, void* d_ws, size_t ws_size,
                              hipStream_t stream) {
  const float* x      = (const float*)d_in[0];
  const float* qkv_w  = (const float*)d_in[1];
  const float* qkv_b  = (const float*)d_in[2];
  const float* proj_w = (const float*)d_in[3];
  const float* proj_b = (const float*)d_in[4];
  const float* rpb    = (const float*)d_in[5];
  const float* n1w    = (const float*)d_in[6];
  const float* n1b    = (const float*)d_in[7];
  const float* n2w    = (const float*)d_in[8];
  const float* n2b    = (const float*)d_in[9];
  const float* c1w    = (const float*)d_in[10];
  const float* c1b    = (const float*)d_in[11];
  const float* c2w    = (const float*)d_in[12];
  const float* c2b    = (const float*)d_in[13];
  const float* ca1w   = (const float*)d_in[14];
  const float* ca1b   = (const float*)d_in[15];
  const float* ca2w   = (const float*)d_in[16];
  const float* ca2b   = (const float*)d_in[17];
  const float* fc1w   = (const float*)d_in[18];
  const float* fc1b   = (const float*)d_in[19];
  const float* fc2w   = (const float*)d_in[20];
  const float* fc2b   = (const float*)d_in[21];
  const int*   rpi    = (const int*)d_in[22];
  (void)in_sizes; (void)n_in; (void)out_size; (void)ws_size;

  // ---- workspace layout: peak ~212.3 MB (< 256 MiB) ----
  char* wsb = (char*)d_ws;
  bf16*  xn    = (bf16*)(wsb + 0);            // 25,165,824
  bf16*  yn    = (bf16*)(wsb + 0);            // alias xn (dead after conv1m)
  float* biasT = (float*)(wsb + 25165824);    //  1,572,864
  bf16*  Qg    = (bf16*)(wsb + 26738688);     // 25,165,824
  bf16*  Kg    = (bf16*)(wsb + 51904512);     // 25,165,824
  bf16*  Vg    = (bf16*)(wsb + 77070336);     // 25,165,824
  bf16*  AO    = (bf16*)(wsb + 102236160);    // 25,165,824
  bf16*  hbuf  = (bf16*)(wsb + 26738688);     // alias Qg..AO (100,663,296; dead after proj)
  float* y     = (float*)(wsb + 127401984);   // 50,331,648
  bf16*  cv1   = (bf16*)(wsb + 177733632);    //  8,388,608
  bf16*  cv2   = (bf16*)(wsb + 186122240);    // 25,165,824
  float* pool  = (float*)(wsb + 211288064);   //      3,072
  float* cavec = (float*)(wsb + 211291136);   //      3,072
  bf16*  wT1   = (bf16*)(wsb + 211294208);    //    221,184  [9][64][192]
  bf16*  wT2   = (bf16*)(wsb + 211515392);    //    221,184  [9][192][64]
  bf16*  wF1   = (bf16*)(wsb + 211736576);    //    294,912  [768][192]
  bf16*  wF2   = (bf16*)(wsb + 212031488);    //    294,912  [192][768]
  float* out   = (float*)d_out;               // end 212,326,400

  k_ln1<<<TTOT / 4, 256, 0, stream>>>(x, n1w, n1b, xn);
  k_bias<<<NHEAD * NTOK, 256, 0, stream>>>(rpi, rpb, biasT);
  k_wprep<<<432, 256, 0, stream>>>(c1w, c2w, wT1, wT2);
  k_wprep2<<<576, 256, 0, stream>>>(fc1w, fc2w, wF1, wF2);
  k_qkvg<<<TTOT / 16, 192, 0, stream>>>(xn, qkv_w, qkv_b, Qg, Kg, Vg);
  k_attn<<<BB * 64 * NHEAD, 256, 0, stream>>>(Qg, Kg, Vg, biasT, AO);
  k_proj<<<TTOT / 4, 256, 0, stream>>>(AO, proj_w, proj_b, x, y);
  k_conv1m<<<1024, 256, 0, stream>>>(xn, wT1, c1b, cv1);
  k_conv2m<<<1024, 256, 0, stream>>>(cv1, wT2, c2b, cv2);
  hipMemsetAsync(pool, 0, BB * CC * sizeof(float), stream);
  k_pool<<<512, 256, 0, stream>>>(cv2, pool);
  k_ca<<<BB, 192, 0, stream>>>(pool, ca1w, ca1b, ca2w, ca2b, cavec);
  k_ln2<<<TTOT / 4, 256, 0, stream>>>(y, cv2, cavec, n2w, n2b, yn);
  k_fc1<<<TTOT / 16, 256, 0, stream>>>(yn, wF1, fc1b, hbuf);
  k_fc2<<<TTOT / 16, 256, 0, stream>>>(hbuf, wF2, fc2b, y, cv2, cavec, out);
}

// Round 10
// 1038.988 us; speedup vs baseline: 4.4092x; 1.5183x over previous
//
#include <hip/hip_runtime.h>
#include <hip/hip_bf16.h>
#include <cstdint>
#include <cstddef>

#define BB 4
#define CC 192
#define NHEAD 6
#define WSZ 16
#define SSH 8
#define NTOK 256
#define HD 32
#define HWPIX 16384
#define TTOT 65536
#define WWID 128
#define SCALE_Q 0.17677669529663687f
#define CONV_SC 0.01f
#define PSTR 264   // LDS row stride (shorts): 16B-aligned, <=2-way banks

typedef __hip_bfloat16 bf16;
typedef __attribute__((ext_vector_type(8))) short short8;
typedef __attribute__((ext_vector_type(4))) float float4v;

__device__ __forceinline__ float b2f(bf16 v) { return __bfloat162float(v); }
__device__ __forceinline__ bf16 f2b(float v) { return __float2bfloat16(v); }
__device__ __forceinline__ unsigned short f2bu(float f) {
  bf16 h = __float2bfloat16(f);
  return *reinterpret_cast<unsigned short*>(&h);
}
__device__ __forceinline__ float gelu_exact(float x) {
  return 0.5f * x * (1.0f + erff(x * 0.7071067811865475f));
}
__device__ __forceinline__ short8 ld8z(const bf16* p, bool ok) {
  if (ok) return *(const short8*)p;
  short8 z = {0, 0, 0, 0, 0, 0, 0, 0};
  return z;
}

// ---------------- K1: LayerNorm1 (x fp32 -> xn bf16). 1 wave per token -----
__global__ __launch_bounds__(256) void k_ln1(const float* __restrict__ x,
                                             const float* __restrict__ g,
                                             const float* __restrict__ b,
                                             bf16* __restrict__ xn) {
  int wv = threadIdx.x >> 6, lane = threadIdx.x & 63;
  int tok = blockIdx.x * 4 + wv;
  size_t row = (size_t)tok * CC;
  float v0 = x[row + lane], v1 = x[row + lane + 64], v2 = x[row + lane + 128];
  float s = v0 + v1 + v2, ss = v0 * v0 + v1 * v1 + v2 * v2;
#pragma unroll
  for (int off = 1; off < 64; off <<= 1) {
    s += __shfl_xor(s, off, 64);
    ss += __shfl_xor(ss, off, 64);
  }
  float mean = s * (1.0f / CC);
  float rstd = rsqrtf(ss * (1.0f / CC) - mean * mean + 1e-5f);
  xn[row + lane]       = f2b((v0 - mean) * rstd * g[lane]       + b[lane]);
  xn[row + lane + 64]  = f2b((v1 - mean) * rstd * g[lane + 64]  + b[lane + 64]);
  xn[row + lane + 128] = f2b((v2 - mean) * rstd * g[lane + 128] + b[lane + 128]);
}

// ------------- K2: bias gather biasQ[h][query][key] (fp32) ------------------
__global__ __launch_bounds__(256) void k_biasq(const int* __restrict__ rpi,
                                               const float* __restrict__ rpb,
                                               float* __restrict__ biasQ) {
  int k = threadIdx.x;
  int h = blockIdx.x >> 8;
  int q = blockIdx.x & 255;
  biasQ[(size_t)blockIdx.x * 256 + k] = rpb[rpi[q * 256 + k] * NHEAD + h];
}

// ------- K2b: conv weight transpose to [tap][oc][ci] bf16 -------------------
__global__ __launch_bounds__(256) void k_wprep(const float* __restrict__ c1w,
                                               const float* __restrict__ c2w,
                                               bf16* __restrict__ wT1,
                                               bf16* __restrict__ wT2) {
  int i = blockIdx.x * 256 + threadIdx.x;   // 0 .. 110591
  {
    int tap = i / (64 * 192); int r = i % (64 * 192);
    int oc = r / 192, ci = r % 192;
    wT1[i] = f2b(c1w[(size_t)(tap * 192 + ci) * 64 + oc]);
  }
  {
    int tap = i / (192 * 64); int r = i % (192 * 64);
    int oc = r / 64, ci = r % 64;
    wT2[i] = f2b(c2w[(size_t)(tap * 64 + ci) * 192 + oc]);
  }
}

// ------- K2c: MLP weight transpose to n-major bf16 --------------------------
__global__ __launch_bounds__(256) void k_wprep2(const float* __restrict__ fc1w,
                                                const float* __restrict__ fc2w,
                                                bf16* __restrict__ wF1,
                                                bf16* __restrict__ wF2) {
  int i = blockIdx.x * 256 + threadIdx.x;   // 0 .. 147455
  {
    int n = i / 192, k = i % 192;           // wF1[n][k], n<768 k<192
    wF1[i] = f2b(fc1w[(size_t)k * 768 + n]);
  }
  {
    int n = i / 768, k = i % 768;           // wF2[n][k], n<192 k<768
    wF2[i] = f2b(fc2w[(size_t)k * 192 + n]);
  }
}

// ------- K2d: qkv/proj weight transpose to n-major bf16 ---------------------
__global__ __launch_bounds__(256) void k_wprep3(const float* __restrict__ qkvw,
                                                const float* __restrict__ projw,
                                                bf16* __restrict__ wQv,
                                                bf16* __restrict__ wP) {
  int i = blockIdx.x * 256 + threadIdx.x;   // 0 .. 147455 (grid 576)
  if (i < 576 * 192) {
    int n = i / 192, k = i % 192;           // wQv[n][k], n<576
    wQv[i] = f2b(qkvw[(size_t)k * 576 + n]);
  }
  if (i < 192 * 192) {
    int n = i / 192, k = i % 192;           // wP[n][k]
    wP[i] = f2b(projw[(size_t)k * 192 + n]);
  }
}

// --- K3: QKV GEMM via MFMA (N=576, K=192), gathered scatter store -----------
// grid TTOT/16, block 256 (4 waves). Wave w: cols w*144..+143 (9 tiles).
__global__ __launch_bounds__(256) void k_qkvg2(const bf16* __restrict__ xn,
                                               const bf16* __restrict__ wQv,
                                               const float* __restrict__ qb,
                                               bf16* __restrict__ Qg,
                                               bf16* __restrict__ Kg,
                                               bf16* __restrict__ Vg) {
  int tok0 = blockIdx.x * 16;
  int wave = threadIdx.x >> 6, lane = threadIdx.x & 63;
  int lm = lane & 15, lq = lane >> 4;
  const bf16* arow = xn + (size_t)(tok0 + lm) * CC + lq * 8;
  float4v acc[9];
#pragma unroll
  for (int nt = 0; nt < 9; ++nt) acc[nt] = (float4v){0.f, 0.f, 0.f, 0.f};
#pragma unroll
  for (int ks = 0; ks < 6; ++ks) {
    short8 afrag = *(const short8*)(arow + ks * 32);
#pragma unroll
    for (int nt = 0; nt < 9; ++nt) {
      int col = wave * 144 + nt * 16 + lm;
      short8 bfrag = *(const short8*)(wQv + (size_t)col * CC + ks * 32 + lq * 8);
      acc[nt] = __builtin_amdgcn_mfma_f32_16x16x32_bf16(afrag, bfrag, acc[nt], 0, 0, 0);
    }
  }
  // per-reg token -> gathered (window,head) coords
  size_t base[4];
#pragma unroll
  for (int reg = 0; reg < 4; ++reg) {
    int tg = tok0 + lq * 4 + reg;
    int b = tg >> 14;
    int pix = tg & 16383;
    int gh = pix >> 7, gw = pix & 127;
    int hs = (gh + 120) & 127, wsx = (gw + 120) & 127;
    int wdx = (b << 6) + ((hs >> 4) << 3) + (wsx >> 4);
    int ndx = ((hs & 15) << 4) + (wsx & 15);
    base[reg] = ((size_t)wdx * NHEAD) * NTOK * HD + (size_t)ndx * HD;  // + head*NTOK*HD + d
  }
#pragma unroll
  for (int nt = 0; nt < 9; ++nt) {
    int col = wave * 144 + nt * 16 + lm;
    float bias = qb[col];
    int sect = col / 192, within = col - sect * 192;
    int head = within >> 5, d = within & 31;
    bf16* dst = (sect == 0) ? Qg : (sect == 1) ? Kg : Vg;
    float scale = (sect == 0) ? SCALE_Q : 1.f;
#pragma unroll
    for (int reg = 0; reg < 4; ++reg) {
      dst[base[reg] + (size_t)head * NTOK * HD + d] = f2b((acc[nt][reg] + bias) * scale);
    }
  }
}

// --- K4: windowed attention via MFMA --------------------------------------
// grid = 1536*2 (wh, query-half). block 256 = 4 waves x 32 queries.
// S = Q*K^T (MFMA), full softmax per 16-row tile, P->LDS bf16, O = P*V (MFMA).
__global__ __launch_bounds__(256) void k_attn2(const bf16* __restrict__ Qg,
                                               const bf16* __restrict__ Kg,
                                               const bf16* __restrict__ Vg,
                                               const float* __restrict__ biasQ,
                                               bf16* __restrict__ AO) {
  __shared__ unsigned short PTw[4][16 * PSTR];  // 33,792 B (wave-private P tiles)
  __shared__ unsigned short VT[32 * PSTR];      // 16,896 B (V transposed)
  int wh = blockIdx.x >> 1, half = blockIdx.x & 1;
  int wdx = wh / NHEAD, h = wh - wdx * NHEAD;
  int wl = wdx & 63;
  int wr = wl >> 3, wc = wl & 7;
  int tid = threadIdx.x;
  int wave = tid >> 6, lane = tid & 63;
  int lm = lane & 15, lq = lane >> 4;
  int q0 = half * 128;

  // stage V^T: thread tid handles key row tid
  {
    const uint4* vp = (const uint4*)(Vg + ((size_t)wh * NTOK + tid) * HD);
    uint4 vv[4] = {vp[0], vp[1], vp[2], vp[3]};
#pragma unroll
    for (int i = 0; i < 4; ++i) {
      unsigned arr[4] = {vv[i].x, vv[i].y, vv[i].z, vv[i].w};
#pragma unroll
      for (int j = 0; j < 4; ++j) {
        int d = i * 8 + j * 2;
        VT[d * PSTR + tid]       = (unsigned short)(arr[j] & 0xffffu);
        VT[(d + 1) * PSTR + tid] = (unsigned short)(arr[j] >> 16);
      }
    }
  }
  __syncthreads();

  int wsk = (wc << 4) + lm;                       // lane's key col (w coord)
  int ridk_w = (wsk >= 112) + (wsk >= 120);
  unsigned short* PT = &PTw[wave][0];

  float4v oacc[2][2];
#pragma unroll
  for (int rt = 0; rt < 2; ++rt)
#pragma unroll
    for (int c2 = 0; c2 < 2; ++c2) oacc[rt][c2] = (float4v){0.f, 0.f, 0.f, 0.f};
  float linv[2][4];

#pragma unroll
  for (int rt = 0; rt < 2; ++rt) {
    int qrow = q0 + wave * 32 + rt * 16;
    short8 aq = *(const short8*)(Qg + ((size_t)wh * NTOK + qrow + lm) * HD + lq * 8);
    float4v sacc[16];
#pragma unroll
    for (int ct = 0; ct < 16; ++ct) sacc[ct] = (float4v){0.f, 0.f, 0.f, 0.f};
#pragma unroll
    for (int ct = 0; ct < 16; ++ct) {
      short8 kf = *(const short8*)(Kg + ((size_t)wh * NTOK + ct * 16 + lm) * HD + lq * 8);
      sacc[ct] = __builtin_amdgcn_mfma_f32_16x16x32_bf16(aq, kf, sacc[ct], 0, 0, 0);
    }
    // softmax over 256 keys, rows lq*4+reg of this 16-row tile
#pragma unroll
    for (int reg = 0; reg < 4; ++reg) {
      int nq = qrow + lq * 4 + reg;
      int hsq = (wr << 4) + (nq >> 4), wsq = (wc << 4) + (nq & 15);
      int ridq = ((hsq >= 112) + (hsq >= 120)) * 3 + ((wsq >= 112) + (wsq >= 120));
      const float* bq = biasQ + ((size_t)(h * 256 + nq)) * 256 + lm;
      float sv[16];
      float mx = -1.0e30f;
#pragma unroll
      for (int ct = 0; ct < 16; ++ct) {
        int hsk = (wr << 4) + ct;
        int ridk = ((hsk >= 112) + (hsk >= 120)) * 3 + ridk_w;
        float s = sacc[ct][reg] + bq[ct * 16] + ((ridk != ridq) ? -100.f : 0.f);
        sv[ct] = s;
        mx = fmaxf(mx, s);
      }
#pragma unroll
      for (int off = 1; off < 16; off <<= 1) mx = fmaxf(mx, __shfl_xor(mx, off, 64));
      float l = 0.f;
#pragma unroll
      for (int ct = 0; ct < 16; ++ct) {
        float p = __expf(sv[ct] - mx);
        l += p;
        PT[(lq * 4 + reg) * PSTR + ct * 16 + lm] = f2bu(p);
      }
#pragma unroll
      for (int off = 1; off < 16; off <<= 1) l += __shfl_xor(l, off, 64);
      linv[rt][reg] = 1.f / l;
    }
    // PV for this row tile: A = P rows (wave-private, in-wave LDS ordering)
#pragma unroll
    for (int kb = 0; kb < 8; ++kb) {
      short8 pf = *(const short8*)&PT[lm * PSTR + kb * 32 + lq * 8];
#pragma unroll
      for (int c2 = 0; c2 < 2; ++c2) {
        short8 vf = *(const short8*)&VT[(c2 * 16 + lm) * PSTR + kb * 32 + lq * 8];
        oacc[rt][c2] = __builtin_amdgcn_mfma_f32_16x16x32_bf16(pf, vf, oacc[rt][c2], 0, 0, 0);
      }
    }
  }
  // write AO
#pragma unroll
  for (int rt = 0; rt < 2; ++rt)
#pragma unroll
    for (int c2 = 0; c2 < 2; ++c2) {
      int d = c2 * 16 + lm;
#pragma unroll
      for (int reg = 0; reg < 4; ++reg) {
        int nq = q0 + wave * 32 + rt * 16 + lq * 4 + reg;
        AO[((size_t)wdx * NTOK + nq) * CC + h * HD + d] =
            f2b(oacc[rt][c2][reg] * linv[rt][reg]);
      }
    }
}

// --- K5: proj GEMM via MFMA (N=192, K=192) + shift-reverse + x residual -----
// grid TTOT/16 (win-order rows), block 256 (4 waves). Wave w: cols w*48..+47.
__global__ __launch_bounds__(256) void k_proj2(const bf16* __restrict__ AO,
                                               const bf16* __restrict__ wP,
                                               const float* __restrict__ pb,
                                               const float* __restrict__ x,
                                               float* __restrict__ y) {
  int r0 = blockIdx.x * 16;
  int wave = threadIdx.x >> 6, lane = threadIdx.x & 63;
  int lm = lane & 15, lq = lane >> 4;
  const bf16* arow = AO + (size_t)(r0 + lm) * CC + lq * 8;
  float4v acc[3];
#pragma unroll
  for (int nt = 0; nt < 3; ++nt) acc[nt] = (float4v){0.f, 0.f, 0.f, 0.f};
#pragma unroll
  for (int ks = 0; ks < 6; ++ks) {
    short8 afrag = *(const short8*)(arow + ks * 32);
#pragma unroll
    for (int nt = 0; nt < 3; ++nt) {
      int col = wave * 48 + nt * 16 + lm;
      short8 bfrag = *(const short8*)(wP + (size_t)col * CC + ks * 32 + lq * 8);
      acc[nt] = __builtin_amdgcn_mfma_f32_16x16x32_bf16(afrag, bfrag, acc[nt], 0, 0, 0);
    }
  }
  size_t drow[4];
#pragma unroll
  for (int reg = 0; reg < 4; ++reg) {
    int r = r0 + lq * 4 + reg;
    int wdx = r >> 8, n = r & 255;
    int wb = wdx >> 6, wl = wdx & 63;
    int hs = ((wl >> 3) << 4) + (n >> 4);
    int wsx = ((wl & 7) << 4) + (n & 15);
    int gh = (hs + SSH) & 127, gw = (wsx + SSH) & 127;
    drow[reg] = ((size_t)wb * HWPIX + (size_t)gh * WWID + gw) * CC;
  }
#pragma unroll
  for (int nt = 0; nt < 3; ++nt) {
    int col = wave * 48 + nt * 16 + lm;
    float bias = pb[col];
#pragma unroll
    for (int reg = 0; reg < 4; ++reg) {
      y[drow[reg] + col] = x[drow[reg] + col] + acc[nt][reg] + bias;
    }
  }
}

// ---- K6: conv3x3 192->64 + GELU via MFMA implicit GEMM ---------------------
__global__ __launch_bounds__(256) void k_conv1m(const bf16* __restrict__ xn,
                                                const bf16* __restrict__ wT1,
                                                const float* __restrict__ c1b,
                                                bf16* __restrict__ cv1) {
  int bi = blockIdx.x;
  int seg = bi & 1, hh = (bi >> 1) & 127, b = bi >> 8;
  int px0 = seg * 64;
  int wave = threadIdx.x >> 6, lane = threadIdx.x & 63;
  int lm = lane & 15, lq = lane >> 4;
  int oc = wave * 16 + lm;
  float4v acc[4];
#pragma unroll
  for (int t = 0; t < 4; ++t) acc[t] = (float4v){0.f, 0.f, 0.f, 0.f};
#pragma unroll
  for (int tap = 0; tap < 9; ++tap) {
    int kh = tap / 3, kw = tap % 3;
    int gh = hh + kh - 1;
    bool rowok = ((unsigned)gh < 128u);
    const bf16* wrow = wT1 + ((size_t)tap * 64 + oc) * CC + lq * 8;
    const bf16* xrow = xn + ((size_t)b * HWPIX + (size_t)gh * WWID) * CC + lq * 8;
#pragma unroll
    for (int ks = 0; ks < 6; ++ks) {
      short8 bfrag = *(const short8*)(wrow + ks * 32);
#pragma unroll
      for (int t = 0; t < 4; ++t) {
        int px = px0 + t * 16 + lm + kw - 1;
        short8 afrag = ld8z(xrow + (size_t)px * CC + ks * 32,
                            rowok && ((unsigned)px < 128u));
        acc[t] = __builtin_amdgcn_mfma_f32_16x16x32_bf16(afrag, bfrag, acc[t], 0, 0, 0);
      }
    }
  }
  float bias = c1b[oc];
#pragma unroll
  for (int t = 0; t < 4; ++t) {
    int pxb = px0 + t * 16 + lq * 4;
    size_t base = ((size_t)b * HWPIX + (size_t)hh * WWID + pxb) * 64 + oc;
    cv1[base]       = f2b(gelu_exact(acc[t][0] + bias));
    cv1[base + 64]  = f2b(gelu_exact(acc[t][1] + bias));
    cv1[base + 128] = f2b(gelu_exact(acc[t][2] + bias));
    cv1[base + 192] = f2b(gelu_exact(acc[t][3] + bias));
  }
}

// ---- K7: conv3x3 64->192 + bias via MFMA implicit GEMM ---------------------
__global__ __launch_bounds__(256) void k_conv2m(const bf16* __restrict__ cv1,
                                                const bf16* __restrict__ wT2,
                                                const float* __restrict__ c2b,
                                                bf16* __restrict__ cv2) {
  int bi = blockIdx.x;
  int seg = bi & 1, hh = (bi >> 1) & 127, b = bi >> 8;
  int px0 = seg * 64;
  int wave = threadIdx.x >> 6, lane = threadIdx.x & 63;
  int lm = lane & 15, lq = lane >> 4;
  float4v acc[3][4];
#pragma unroll
  for (int nt = 0; nt < 3; ++nt)
#pragma unroll
    for (int t = 0; t < 4; ++t) acc[nt][t] = (float4v){0.f, 0.f, 0.f, 0.f};
#pragma unroll
  for (int tap = 0; tap < 9; ++tap) {
    int kh = tap / 3, kw = tap % 3;
    int gh = hh + kh - 1;
    bool rowok = ((unsigned)gh < 128u);
    const bf16* xrow = cv1 + ((size_t)b * HWPIX + (size_t)gh * WWID) * 64 + lq * 8;
#pragma unroll
    for (int ks = 0; ks < 2; ++ks) {
      short8 bfrag[3];
#pragma unroll
      for (int nt = 0; nt < 3; ++nt) {
        int oc = wave * 48 + nt * 16 + lm;
        bfrag[nt] = *(const short8*)(wT2 + ((size_t)tap * 192 + oc) * 64 + ks * 32 + lq * 8);
      }
#pragma unroll
      for (int t = 0; t < 4; ++t) {
        int px = px0 + t * 16 + lm + kw - 1;
        short8 afrag = ld8z(xrow + (size_t)px * 64 + ks * 32,
                            rowok && ((unsigned)px < 128u));
#pragma unroll
        for (int nt = 0; nt < 3; ++nt)
          acc[nt][t] = __builtin_amdgcn_mfma_f32_16x16x32_bf16(afrag, bfrag[nt], acc[nt][t], 0, 0, 0);
      }
    }
  }
#pragma unroll
  for (int nt = 0; nt < 3; ++nt) {
    int oc = wave * 48 + nt * 16 + lm;
    float bias = c2b[oc];
#pragma unroll
    for (int t = 0; t < 4; ++t) {
      int pxb = px0 + t * 16 + lq * 4;
      size_t base = ((size_t)b * HWPIX + (size_t)hh * WWID + pxb) * CC + oc;
      cv2[base]           = f2b(acc[nt][t][0] + bias);
      cv2[base + CC]      = f2b(acc[nt][t][1] + bias);
      cv2[base + 2 * CC]  = f2b(acc[nt][t][2] + bias);
      cv2[base + 3 * CC]  = f2b(acc[nt][t][3] + bias);
    }
  }
}

// ---------------- K8: global average pool (sum into pooled, pre-zeroed) ----
__global__ __launch_bounds__(256) void k_pool(const bf16* __restrict__ cv2,
                                              float* __restrict__ pooled) {
  __shared__ float sacc[CC];
  int t = threadIdx.x;
  if (t < CC) sacc[t] = 0.f;
  __syncthreads();
  int b = blockIdx.x >> 7;
  int pc = blockIdx.x & 127;
  const bf16* base = cv2 + (size_t)b * HWPIX * CC + (size_t)pc * 128 * CC;
  for (int it = 0; it < 96; ++it) {
    int e = it * 256 + t;
    atomicAdd(&sacc[e % CC], b2f(base[e]));
  }
  __syncthreads();
  if (t < CC) atomicAdd(&pooled[b * CC + t], sacc[t]);
}

// ---------------- K9: channel attention weights ----------------
__global__ __launch_bounds__(192) void k_ca(const float* __restrict__ pooled,
                                            const float* __restrict__ w1,
                                            const float* __restrict__ b1,
                                            const float* __restrict__ w2,
                                            const float* __restrict__ b2,
                                            float* __restrict__ ca) {
  __shared__ float pld[CC];
  __shared__ float t1[6];
  int t = threadIdx.x, b = blockIdx.x;
  pld[t] = pooled[b * CC + t] * (1.0f / HWPIX);
  __syncthreads();
  if (t < 6) {
    float s = b1[t];
    for (int c = 0; c < CC; ++c) s += pld[c] * w1[c * 6 + t];
    t1[t] = fmaxf(s, 0.f);
  }
  __syncthreads();
  float s = b2[t];
#pragma unroll
  for (int k = 0; k < 6; ++k) s += t1[k] * w2[k * CC + t];
  ca[b * CC + t] = 1.f / (1.f + __expf(-s));
}

// --- K10: LN2 with conv-branch fold: yn = LN(y + cv2*ca*0.01) bf16 ---------
__global__ __launch_bounds__(256) void k_ln2(const float* __restrict__ y,
                                             const bf16* __restrict__ cv2,
                                             const float* __restrict__ ca,
                                             const float* __restrict__ g2,
                                             const float* __restrict__ b2,
                                             bf16* __restrict__ yn) {
  int wv = threadIdx.x >> 6, lane = threadIdx.x & 63;
  int tok = blockIdx.x * 4 + wv;
  const float* cab = ca + (tok >> 14) * CC;
  size_t row = (size_t)tok * CC;
  float v0 = y[row + lane]       + b2f(cv2[row + lane])       * cab[lane]       * CONV_SC;
  float v1 = y[row + lane + 64]  + b2f(cv2[row + lane + 64])  * cab[lane + 64]  * CONV_SC;
  float v2 = y[row + lane + 128] + b2f(cv2[row + lane + 128]) * cab[lane + 128] * CONV_SC;
  float s = v0 + v1 + v2, ss = v0 * v0 + v1 * v1 + v2 * v2;
#pragma unroll
  for (int off = 1; off < 64; off <<= 1) {
    s += __shfl_xor(s, off, 64);
    ss += __shfl_xor(ss, off, 64);
  }
  float mean = s * (1.0f / CC);
  float rstd = rsqrtf(ss * (1.0f / CC) - mean * mean + 1e-5f);
  yn[row + lane]       = f2b((v0 - mean) * rstd * g2[lane]       + b2[lane]);
  yn[row + lane + 64]  = f2b((v1 - mean) * rstd * g2[lane + 64]  + b2[lane + 64]);
  yn[row + lane + 128] = f2b((v2 - mean) * rstd * g2[lane + 128] + b2[lane + 128]);
}

// --- K11: fc1 GEMM (K=192, N=768) + GELU via MFMA -> h bf16 -----------------
__global__ __launch_bounds__(256) void k_fc1(const bf16* __restrict__ yn,
                                             const bf16* __restrict__ wF1,
                                             const float* __restrict__ fb1,
                                             bf16* __restrict__ h) {
  int tok0 = blockIdx.x * 16;
  int wave = threadIdx.x >> 6, lane = threadIdx.x & 63;
  int lm = lane & 15, lq = lane >> 4;
  const bf16* arow = yn + (size_t)(tok0 + lm) * CC + lq * 8;
  float4v acc[12];
#pragma unroll
  for (int nt = 0; nt < 12; ++nt) acc[nt] = (float4v){0.f, 0.f, 0.f, 0.f};
#pragma unroll
  for (int ks = 0; ks < 6; ++ks) {
    short8 afrag = *(const short8*)(arow + ks * 32);
#pragma unroll
    for (int nt = 0; nt < 12; ++nt) {
      int col = wave * 192 + nt * 16 + lm;
      short8 bfrag = *(const short8*)(wF1 + (size_t)col * CC + ks * 32 + lq * 8);
      acc[nt] = __builtin_amdgcn_mfma_f32_16x16x32_bf16(afrag, bfrag, acc[nt], 0, 0, 0);
    }
  }
#pragma unroll
  for (int nt = 0; nt < 12; ++nt) {
    int col = wave * 192 + nt * 16 + lm;
    float bias = fb1[col];
    size_t base = (size_t)(tok0 + lq * 4) * 768 + col;
    h[base]         = f2b(gelu_exact(acc[nt][0] + bias));
    h[base + 768]   = f2b(gelu_exact(acc[nt][1] + bias));
    h[base + 1536]  = f2b(gelu_exact(acc[nt][2] + bias));
    h[base + 2304]  = f2b(gelu_exact(acc[nt][3] + bias));
  }
}

// --- K12: fc2 GEMM (K=768, N=192) + residual epilogue via MFMA --------------
__global__ __launch_bounds__(256) void k_fc2(const bf16* __restrict__ h,
                                             const bf16* __restrict__ wF2,
                                             const float* __restrict__ fb2,
                                             const float* __restrict__ y,
                                             const bf16* __restrict__ cv2,
                                             const float* __restrict__ ca,
                                             float* __restrict__ out) {
  int tok0 = blockIdx.x * 16;
  int wave = threadIdx.x >> 6, lane = threadIdx.x & 63;
  int lm = lane & 15, lq = lane >> 4;
  const bf16* arow = h + (size_t)(tok0 + lm) * 768 + lq * 8;
  float4v acc[3];
#pragma unroll
  for (int nt = 0; nt < 3; ++nt) acc[nt] = (float4v){0.f, 0.f, 0.f, 0.f};
#pragma unroll
  for (int ks = 0; ks < 24; ++ks) {
    short8 afrag = *(const short8*)(arow + ks * 32);
#pragma unroll
    for (int nt = 0; nt < 3; ++nt) {
      int col = wave * 48 + nt * 16 + lm;
      short8 bfrag = *(const short8*)(wF2 + (size_t)col * 768 + ks * 32 + lq * 8);
      acc[nt] = __builtin_amdgcn_mfma_f32_16x16x32_bf16(afrag, bfrag, acc[nt], 0, 0, 0);
    }
  }
  const float* cab = ca + (tok0 >> 14) * CC;
#pragma unroll
  for (int nt = 0; nt < 3; ++nt) {
    int col = wave * 48 + nt * 16 + lm;
    float bias = fb2[col];
#pragma unroll
    for (int reg = 0; reg < 4; ++reg) {
      int tok = tok0 + lq * 4 + reg;
      size_t idx = (size_t)tok * CC + col;
      float yf = y[idx] + b2f(cv2[idx]) * cab[col] * CONV_SC;
      out[idx] = yf + acc[nt][reg] + bias;
    }
  }
}

extern "C" void kernel_launch(void* const* d_in, const int* in_sizes, int n_in,
                              void* d_out, int out_size, void* d_ws, size_t ws_size,
                              hipStream_t stream) {
  const float* x      = (const float*)d_in[0];
  const float* qkv_w  = (const float*)d_in[1];
  const float* qkv_b  = (const float*)d_in[2];
  const float* proj_w = (const float*)d_in[3];
  const float* proj_b = (const float*)d_in[4];
  const float* rpb    = (const float*)d_in[5];
  const float* n1w    = (const float*)d_in[6];
  const float* n1b    = (const float*)d_in[7];
  const float* n2w    = (const float*)d_in[8];
  const float* n2b    = (const float*)d_in[9];
  const float* c1w    = (const float*)d_in[10];
  const float* c1b    = (const float*)d_in[11];
  const float* c2w    = (const float*)d_in[12];
  const float* c2b    = (const float*)d_in[13];
  const float* ca1w   = (const float*)d_in[14];
  const float* ca1b   = (const float*)d_in[15];
  const float* ca2w   = (const float*)d_in[16];
  const float* ca2b   = (const float*)d_in[17];
  const float* fc1w   = (const float*)d_in[18];
  const float* fc1b   = (const float*)d_in[19];
  const float* fc2w   = (const float*)d_in[20];
  const float* fc2b   = (const float*)d_in[21];
  const int*   rpi    = (const int*)d_in[22];
  (void)in_sizes; (void)n_in; (void)out_size; (void)ws_size;

  // ---- workspace layout: peak ~212.6 MB (< 256 MiB) ----
  char* wsb = (char*)d_ws;
  bf16*  xn    = (bf16*)(wsb + 0);            // 25,165,824
  bf16*  yn    = (bf16*)(wsb + 0);            // alias xn (dead after conv1m)
  float* biasQ = (float*)(wsb + 25165824);    //  1,572,864
  bf16*  Qg    = (bf16*)(wsb + 26738688);     // 25,165,824
  bf16*  Kg    = (bf16*)(wsb + 51904512);     // 25,165,824
  bf16*  Vg    = (bf16*)(wsb + 77070336);     // 25,165,824
  bf16*  AO    = (bf16*)(wsb + 102236160);    // 25,165,824
  bf16*  hbuf  = (bf16*)(wsb + 26738688);     // alias Qg..AO (dead after proj2)
  float* y     = (float*)(wsb + 127401984);   // 50,331,648
  bf16*  cv1   = (bf16*)(wsb + 177733632);    //  8,388,608
  bf16*  cv2   = (bf16*)(wsb + 186122240);    // 25,165,824
  float* pool  = (float*)(wsb + 211288064);   //      3,072
  float* cavec = (float*)(wsb + 211291136);   //      3,072
  bf16*  wT1   = (bf16*)(wsb + 211294208);    //    221,184  [9][64][192]
  bf16*  wT2   = (bf16*)(wsb + 211515392);    //    221,184  [9][192][64]
  bf16*  wF1   = (bf16*)(wsb + 211736576);    //    294,912  [768][192]
  bf16*  wF2   = (bf16*)(wsb + 212031488);    //    294,912  [192][768]
  bf16*  wQv   = (bf16*)(wsb + 212326400);    //    221,184  [576][192]
  bf16*  wP    = (bf16*)(wsb + 212547584);    //     73,728  [192][192]
  float* out   = (float*)d_out;               // end 212,621,312

  k_ln1<<<TTOT / 4, 256, 0, stream>>>(x, n1w, n1b, xn);
  k_biasq<<<NHEAD * NTOK, 256, 0, stream>>>(rpi, rpb, biasQ);
  k_wprep<<<432, 256, 0, stream>>>(c1w, c2w, wT1, wT2);
  k_wprep2<<<576, 256, 0, stream>>>(fc1w, fc2w, wF1, wF2);
  k_wprep3<<<576, 256, 0, stream>>>(qkv_w, proj_w, wQv, wP);
  k_qkvg2<<<TTOT / 16, 256, 0, stream>>>(xn, wQv, qkv_b, Qg, Kg, Vg);
  k_attn2<<<BB * 64 * NHEAD * 2, 256, 0, stream>>>(Qg, Kg, Vg, biasQ, AO);
  k_proj2<<<TTOT / 16, 256, 0, stream>>>(AO, wP, proj_b, x, y);
  k_conv1m<<<1024, 256, 0, stream>>>(xn, wT1, c1b, cv1);
  k_conv2m<<<1024, 256, 0, stream>>>(cv1, wT2, c2b, cv2);
  hipMemsetAsync(pool, 0, BB * CC * sizeof(float), stream);
  k_pool<<<512, 256, 0, stream>>>(cv2, pool);
  k_ca<<<BB, 192, 0, stream>>>(pool, ca1w, ca1b, ca2w, ca2b, cavec);
  k_ln2<<<TTOT / 4, 256, 0, stream>>>(y, cv2, cavec, n2w, n2b, yn);
  k_fc1<<<TTOT / 16, 256, 0, stream>>>(yn, wF1, fc1b, hbuf);
  k_fc2<<<TTOT / 16, 256, 0, stream>>>(hbuf, wF2, fc2b, y, cv2, cavec, out);
}